// Round 5
// baseline (266.567 us; speedup 1.0000x reference)
//
#include <hip/hip_runtime.h>

// Stage2GNN v5: v4 + degree-adaptive tail in k_aggregate (8/4/2/1-pair bodies)
// to kill the ~47% dummy edge-slots that the fixed 16-edge granularity caused
// at mean degree ~17.

#define N_NODES 40000
#define N_EDGES 640000
#define DIM     128

typedef unsigned short u16;
typedef __attribute__((ext_vector_type(8))) short bf16x8;
typedef __attribute__((ext_vector_type(4))) float f32x4;

__device__ __forceinline__ u16 f2bf(float v) {
    unsigned u = __float_as_uint(v);
    u += 0x7FFFu + ((u >> 16) & 1u);
    return (u16)(u >> 16);
}
__device__ __forceinline__ float bf2f(u16 h) { return __uint_as_float(((unsigned)h) << 16); }
__device__ __forceinline__ float rdlane_f(float v, int l) {
    return __uint_as_float(__builtin_amdgcn_readlane(__float_as_uint(v), l));
}

// ---------------- input conversion + deg init ----------------
__global__ __launch_bounds__(256) void k_xcvt(const float* __restrict__ x,
                                              u16* __restrict__ xh, u16* __restrict__ xl,
                                              int* __restrict__ deg, int* __restrict__ counter) {
    int i = blockIdx.x * 256 + threadIdx.x;       // float4 index
    if (i < N_NODES) deg[i] = 1;                  // self loop
    if (i == 0) *counter = 0;
    const int n4 = N_NODES * DIM / 4;
    if (i >= n4) return;
    float4 v = ((const float4*)x)[i];
    u16 h0 = f2bf(v.x), h1 = f2bf(v.y), h2 = f2bf(v.z), h3 = f2bf(v.w);
    u16 l0 = f2bf(v.x - bf2f(h0)), l1 = f2bf(v.y - bf2f(h1));
    u16 l2 = f2bf(v.z - bf2f(h2)), l3 = f2bf(v.w - bf2f(h3));
    ((ushort4*)xh)[i] = make_ushort4(h0, h1, h2, h3);
    ((ushort4*)xl)[i] = make_ushort4(l0, l1, l2, l3);
}

__global__ __launch_bounds__(256) void k_wcvt(
    const float* __restrict__ satW, const float* __restrict__ neiW,
    const float* __restrict__ c1W, const float* __restrict__ c2W,
    const float* __restrict__ f1W, const float* __restrict__ f2W,
    u16* __restrict__ wa) {
    int m = blockIdx.y;
    const float* src; int C, K, Cp; int offH, offL;
    switch (m) {
        case 0: src = satW; C = 128; K = 64;  Cp = 128; offH = 0;      offL = 8192;   break;
        case 1: src = neiW; C = 128; K = 64;  Cp = 128; offH = 16384;  offL = 24576;  break;
        case 2: src = c1W;  C = 128; K = 128; Cp = 128; offH = 32768;  offL = 49152;  break;
        case 3: src = c2W;  C = 128; K = 128; Cp = 128; offH = 65536;  offL = 81920;  break;
        case 4: src = f1W;  C = 128; K = 128; Cp = 128; offH = 98304;  offL = 114688; break;
        default:src = f2W;  C = 54;  K = 128; Cp = 64;  offH = 131072; offL = 139264; break;
    }
    int e = blockIdx.x * 256 + threadIdx.x;
    if (e >= Cp * K) return;
    int c = e / K, k = e - c * K;
    float v = (c < C) ? src[c * K + k] : 0.f;
    u16 h = f2bf(v);
    wa[offH + e] = h;
    wa[offL + e] = f2bf(v - bf2f(h));
}

// ---------------- CSR build ----------------
__global__ void k_deg_count(const int* __restrict__ dst, int* __restrict__ deg) {
    int t = blockIdx.x * 256 + threadIdx.x;
    if (t < N_EDGES) atomicAdd(&deg[dst[t]], 1);
}
__global__ void k_assign(const int* __restrict__ deg, int* __restrict__ counter,
                         int* __restrict__ start, int* __restrict__ cursor,
                         int* __restrict__ csr_src) {
    int i = blockIdx.x * 256 + threadIdx.x;
    if (i >= N_NODES) return;
    int d = deg[i];
    int s = atomicAdd(counter, d);
    start[i] = s;
    csr_src[s] = i;
    cursor[i] = s + 1;
}
__global__ void k_fill_edges(const int* __restrict__ src, const int* __restrict__ dst,
                             int* __restrict__ cursor, int* __restrict__ csr_src) {
    int t = blockIdx.x * 256 + threadIdx.x;
    if (t < N_EDGES) {
        int p = atomicAdd(&cursor[dst[t]], 1);
        csr_src[p] = src[t];
    }
}

// ---------------- MFMA GEMM: out[r][c] = sum_k A[r][k]*W[c][k], K=128 ----------------
// Split bf16: acc += Ah*Wh + Ah*Wl + Al*Wh. BK=64 chunked W staging (32KB LDS).
enum { EPI_F32RAW = 0, EPI_RELU_BF16 = 1, EPI_BIAS_F32 = 2 };

template<int CT, bool ALPHA, int EPI>
__global__ __launch_bounds__(256) void k_mfma_gemm(
    const u16* __restrict__ Ah, const u16* __restrict__ Al,
    const u16* __restrict__ Wh, const u16* __restrict__ Wl,
    const float* __restrict__ bias, int C,
    float* __restrict__ outF, int ldo,
    u16* __restrict__ outH, u16* __restrict__ outL,
    const float* __restrict__ a_src, const float* __restrict__ a_dst,
    float* __restrict__ as_, float* __restrict__ ad_)
{
    __shared__ u16 Ws[CT * 2 * 2 * 64 * 8];   // [ct][ks2][hilo2][lane64] x 8 u16
    const int tid = threadIdx.x;
    const int lane = tid & 63;
    const int wv = tid >> 6;
    const int r0 = blockIdx.x * 64 + wv * 16;
    const int arow = r0 + (lane & 15);
    const int kb = (lane >> 4) * 8;

    bf16x8 ah[4], al[4];
#pragma unroll
    for (int s = 0; s < 4; ++s) {
        ah[s] = *reinterpret_cast<const bf16x8*>(Ah + (size_t)arow * 128 + s * 32 + kb);
        al[s] = *reinterpret_cast<const bf16x8*>(Al + (size_t)arow * 128 + s * 32 + kb);
    }

    f32x4 acc[CT];
#pragma unroll
    for (int ct = 0; ct < CT; ++ct) acc[ct] = (f32x4){0.f, 0.f, 0.f, 0.f};

#pragma unroll
    for (int kc = 0; kc < 2; ++kc) {
        if (kc) __syncthreads();
        for (int idx = tid; idx < CT * 2 * 2 * 64; idx += 256) {
            int l = idx & 63;
            int q = idx >> 6;
            int hilo = q & 1;
            int ks = (q >> 1) & 1;
            int ct = q >> 2;
            int c = ct * 16 + (l & 15);
            int k = kc * 64 + ks * 32 + (l >> 4) * 8;
            const u16* Wp = hilo ? Wl : Wh;
            bf16x8 wv_ = *reinterpret_cast<const bf16x8*>(Wp + (size_t)c * 128 + k);
            *reinterpret_cast<bf16x8*>(&Ws[idx * 8]) = wv_;
        }
        __syncthreads();
#pragma unroll
        for (int ct = 0; ct < CT; ++ct) {
#pragma unroll
            for (int ks = 0; ks < 2; ++ks) {
                int s = kc * 2 + ks;
                int base = (ct * 2 + ks) * 1024;
                bf16x8 bh = *reinterpret_cast<const bf16x8*>(&Ws[base + lane * 8]);
                bf16x8 bl = *reinterpret_cast<const bf16x8*>(&Ws[base + 512 + lane * 8]);
                acc[ct] = __builtin_amdgcn_mfma_f32_16x16x32_bf16(ah[s], bh, acc[ct], 0, 0, 0);
                acc[ct] = __builtin_amdgcn_mfma_f32_16x16x32_bf16(ah[s], bl, acc[ct], 0, 0, 0);
                acc[ct] = __builtin_amdgcn_mfma_f32_16x16x32_bf16(al[s], bh, acc[ct], 0, 0, 0);
            }
        }
    }

    if constexpr (ALPHA) {
        float ps[4] = {0, 0, 0, 0}, pd[4] = {0, 0, 0, 0};
#pragma unroll
        for (int ct = 0; ct < CT; ++ct) {
            float asv = a_src[ct * 16 + (lane & 15)];
            float adv = a_dst[ct * 16 + (lane & 15)];
#pragma unroll
            for (int r = 0; r < 4; ++r) {
                ps[r] = fmaf(acc[ct][r], asv, ps[r]);
                pd[r] = fmaf(acc[ct][r], adv, pd[r]);
            }
        }
#pragma unroll
        for (int off = 1; off < 16; off <<= 1) {
#pragma unroll
            for (int r = 0; r < 4; ++r) {
                ps[r] += __shfl_xor(ps[r], off);
                pd[r] += __shfl_xor(pd[r], off);
            }
        }
        if ((lane & 15) == 0) {
#pragma unroll
            for (int r = 0; r < 4; ++r) {
                int row = r0 + (lane >> 4) * 4 + r;
                as_[row] = ps[r];
                ad_[row] = pd[r];
            }
        }
    }

#pragma unroll
    for (int ct = 0; ct < CT; ++ct) {
        int c = ct * 16 + (lane & 15);
#pragma unroll
        for (int r = 0; r < 4; ++r) {
            int row = r0 + (lane >> 4) * 4 + r;
            float v = acc[ct][r];
            if constexpr (EPI == EPI_F32RAW) {
                outF[(size_t)row * ldo + c] = v;
            } else if constexpr (EPI == EPI_RELU_BF16) {
                v = fmaxf(v + bias[c], 0.f);
                u16 h = f2bf(v);
                outH[(size_t)row * 128 + c] = h;
                outL[(size_t)row * 128 + c] = f2bf(v - bf2f(h));
            } else {
                if (c < C) outF[(size_t)row * ldo + c] = v + bias[c];
            }
        }
    }
}

// ---------------- fused encoder (two K=64 split-bf16 MFMA GEMMs, staged serially) ----------------
__global__ __launch_bounds__(256) void k_encoder(
    const u16* __restrict__ xh, const u16* __restrict__ xl,
    const u16* __restrict__ sH, const u16* __restrict__ sL,
    const u16* __restrict__ nH, const u16* __restrict__ nL,
    const float* __restrict__ satb, const float* __restrict__ neib,
    u16* __restrict__ outH, u16* __restrict__ outL)
{
    __shared__ u16 Ws[8 * 2 * 2 * 64 * 8];   // 32KB
    const int tid = threadIdx.x;
    const int lane = tid & 63;
    const int wv = tid >> 6;
    const int r0 = blockIdx.x * 64 + wv * 16;
    const int arow = r0 + (lane & 15);
    const int kb = (lane >> 4) * 8;

    bf16x8 axh[4], axl[4];
#pragma unroll
    for (int s = 0; s < 4; ++s) {
        axh[s] = *reinterpret_cast<const bf16x8*>(xh + (size_t)arow * 128 + s * 32 + kb);
        axl[s] = *reinterpret_cast<const bf16x8*>(xl + (size_t)arow * 128 + s * 32 + kb);
    }

    f32x4 accS[8], accN[8];
#pragma unroll
    for (int ct = 0; ct < 8; ++ct) { accS[ct] = (f32x4){0,0,0,0}; accN[ct] = (f32x4){0,0,0,0}; }

#pragma unroll
    for (int mat = 0; mat < 2; ++mat) {
        if (mat) __syncthreads();
        const u16* WH = mat ? nH : sH;
        const u16* WL = mat ? nL : sL;
        for (int idx = tid; idx < 2048; idx += 256) {
            int l = idx & 63;
            int q = idx >> 6;
            int hilo = q & 1;
            int ks = (q >> 1) & 1;
            int ct = q >> 2;
            int c = ct * 16 + (l & 15);
            int k = ks * 32 + (l >> 4) * 8;
            const u16* Wp = hilo ? WL : WH;
            bf16x8 wv_ = *reinterpret_cast<const bf16x8*>(Wp + (size_t)c * 64 + k);
            *reinterpret_cast<bf16x8*>(&Ws[idx * 8]) = wv_;
        }
        __syncthreads();
#pragma unroll
        for (int ct = 0; ct < 8; ++ct) {
#pragma unroll
            for (int ks = 0; ks < 2; ++ks) {
                int s = mat * 2 + ks;    // sat: x slices 0-1; nei: x slices 2-3
                int base = (ct * 2 + ks) * 1024;
                bf16x8 bh = *reinterpret_cast<const bf16x8*>(&Ws[base + lane * 8]);
                bf16x8 bl = *reinterpret_cast<const bf16x8*>(&Ws[base + 512 + lane * 8]);
                f32x4* ac = mat ? &accN[ct] : &accS[ct];
                *ac = __builtin_amdgcn_mfma_f32_16x16x32_bf16(axh[s], bh, *ac, 0, 0, 0);
                *ac = __builtin_amdgcn_mfma_f32_16x16x32_bf16(axh[s], bl, *ac, 0, 0, 0);
                *ac = __builtin_amdgcn_mfma_f32_16x16x32_bf16(axl[s], bh, *ac, 0, 0, 0);
            }
        }
    }

#pragma unroll
    for (int ct = 0; ct < 8; ++ct) {
        int c = ct * 16 + (lane & 15);
        float bs = satb[c], bn = neib[c];
#pragma unroll
        for (int r = 0; r < 4; ++r) {
            int row = r0 + (lane >> 4) * 4 + r;
            float v = fmaxf(accS[ct][r] + bs, 0.f) + 0.5f * fmaxf(accN[ct][r] + bn, 0.f);
            u16 h = f2bf(v);
            outH[(size_t)row * 128 + c] = h;
            outL[(size_t)row * 128 + c] = f2bf(v - bf2f(h));
        }
    }
}

// ---------------- wave-per-node softmax + aggregation ----------------
// 2 edge-rows per wave-op (lanes 0-31 even edge, 32-63 odd edge, float4 dims).
// Degree-adaptive tail: 8-pair main body, then 4/2/1-pair tails so a mean-17
// degree node wastes ~0.5 slots instead of 15.
#define DO_PAIRS(NP, TB)                                                      \
    {                                                                         \
        float pw[NP]; const float4* hp[NP];                                   \
        _Pragma("unroll")                                                     \
        for (int q = 0; q < NP; ++q) {                                        \
            int e0 = (TB) + 2 * q;                                            \
            float plo = rdlane_f(p, e0), phi = rdlane_f(p, e0 + 1);           \
            int jlo = __builtin_amdgcn_readlane(jj, e0);                      \
            int jhi = __builtin_amdgcn_readlane(jj, e0 + 1);                  \
            pw[q] = hodd ? phi : plo;                                         \
            int j = hodd ? jhi : jlo;                                         \
            hp[q] = (const float4*)&h[(size_t)j * DIM + 4 * l32];             \
        }                                                                     \
        float4 hv[NP];                                                        \
        _Pragma("unroll") for (int q = 0; q < NP; ++q) hv[q] = *hp[q];        \
        _Pragma("unroll") for (int q = 0; q < NP; ++q) {                      \
            acc.x = fmaf(pw[q], hv[q].x, acc.x);                              \
            acc.y = fmaf(pw[q], hv[q].y, acc.y);                              \
            acc.z = fmaf(pw[q], hv[q].z, acc.z);                              \
            acc.w = fmaf(pw[q], hv[q].w, acc.w);                              \
        }                                                                     \
    }

__global__ __launch_bounds__(256) void k_aggregate(
    const float* __restrict__ h, const float* __restrict__ as_,
    const float* __restrict__ ad_, const int* __restrict__ start,
    const int* __restrict__ deg, const int* __restrict__ csr_src,
    const float* __restrict__ bias, u16* __restrict__ outH, u16* __restrict__ outL)
{
    int wid = (blockIdx.x * 256 + threadIdx.x) >> 6;
    int lane = threadIdx.x & 63;
    if (wid >= N_NODES) return;

    const int s0 = start[wid];
    const int s1 = s0 + deg[wid];
    const float adi = ad_[wid];
    const int l32 = lane & 31;
    const bool hodd = lane >= 32;

    float4 acc = make_float4(0.f, 0.f, 0.f, 0.f);
    float ssum = 0.f;
    for (int base = s0; base < s1; base += 64) {
        int k = base + lane;
        int cnt = min(64, s1 - base);   // wave-uniform
        int jj = 0;
        float p = 0.f;
        if (k < s1) {
            jj = csr_src[k];
            float e = as_[jj] + adi;
            e = (e > 0.f) ? e : 0.2f * e;
            p = __expf(e);              // |e| << 88: no max-shift needed
            ssum += p;
        }
        int t = 0;
        for (; t + 16 <= cnt; t += 16) DO_PAIRS(8, t)
        if (t + 8 <= cnt) { DO_PAIRS(4, t) t += 8; }
        if (t + 4 <= cnt) { DO_PAIRS(2, t) t += 4; }
        for (; t < cnt; t += 2) DO_PAIRS(1, t)   // final pair may hold 1 dummy
    }
#pragma unroll
    for (int off = 32; off; off >>= 1) ssum += __shfl_xor(ssum, off);
    acc.x += __shfl_xor(acc.x, 32);
    acc.y += __shfl_xor(acc.y, 32);
    acc.z += __shfl_xor(acc.z, 32);
    acc.w += __shfl_xor(acc.w, 32);
    float inv = 1.f / (ssum + 1e-16f);

    if (!hodd) {
        float4 bv = *(const float4*)&bias[4 * l32];
        float o0 = fmaxf(fmaf(acc.x, inv, bv.x), 0.f);
        float o1 = fmaxf(fmaf(acc.y, inv, bv.y), 0.f);
        float o2 = fmaxf(fmaf(acc.z, inv, bv.z), 0.f);
        float o3 = fmaxf(fmaf(acc.w, inv, bv.w), 0.f);
        u16 h0 = f2bf(o0), h1 = f2bf(o1), h2 = f2bf(o2), h3 = f2bf(o3);
        ushort4 hvv = make_ushort4(h0, h1, h2, h3);
        ushort4 lvv = make_ushort4(f2bf(o0 - bf2f(h0)), f2bf(o1 - bf2f(h1)),
                                   f2bf(o2 - bf2f(h2)), f2bf(o3 - bf2f(h3)));
        *(ushort4*)&outH[(size_t)wid * 128 + 4 * l32] = hvv;
        *(ushort4*)&outL[(size_t)wid * 128 + 4 * l32] = lvv;
    }
}

extern "C" void kernel_launch(void* const* d_in, const int* in_sizes, int n_in,
                              void* d_out, int out_size, void* d_ws, size_t ws_size,
                              hipStream_t stream) {
    (void)in_sizes; (void)n_in; (void)out_size; (void)ws_size;

    const float* x       = (const float*)d_in[0];
    const int*   ei      = (const int*)d_in[1];
    const float* sat_W   = (const float*)d_in[2];
    const float* sat_b   = (const float*)d_in[3];
    const float* neigh_W = (const float*)d_in[4];
    const float* neigh_b = (const float*)d_in[5];
    const float* c1_W    = (const float*)d_in[6];
    const float* c1_as   = (const float*)d_in[7];
    const float* c1_ad   = (const float*)d_in[8];
    const float* c1_b    = (const float*)d_in[9];
    const float* c2_W    = (const float*)d_in[10];
    const float* c2_as   = (const float*)d_in[11];
    const float* c2_ad   = (const float*)d_in[12];
    const float* c2_b    = (const float*)d_in[13];
    const float* fc1_W   = (const float*)d_in[14];
    const float* fc1_b   = (const float*)d_in[15];
    const float* fc2_W   = (const float*)d_in[16];
    const float* fc2_b   = (const float*)d_in[17];

    const int* e_src = ei;
    const int* e_dst = ei + N_EDGES;

    char* w = (char*)d_ws;
    float* hB     = (float*)(w);                  // [N,128] f32
    u16*   xH     = (u16*)  (w + 20480000);
    u16*   xL     = (u16*)  (w + 30720000);
    u16*   hH     = (u16*)  (w + 40960000);
    u16*   hL     = (u16*)  (w + 51200000);
    float* as_    = (float*)(w + 61440000);
    float* ad_    = (float*)(w + 61600000);
    int*   deg    = (int*)  (w + 61760000);
    int*   start  = (int*)  (w + 61920000);
    int*   cursor = (int*)  (w + 62080000);
    int*   counter= (int*)  (w + 62240000);
    int*   csr    = (int*)  (w + 62240256);
    u16*   wa     = (u16*)  (w + 64960512);

    u16 *satH = wa,          *satL = wa + 8192;
    u16 *neiH = wa + 16384,  *neiL = wa + 24576;
    u16 *c1H  = wa + 32768,  *c1L  = wa + 49152;
    u16 *c2H  = wa + 65536,  *c2L  = wa + 81920;
    u16 *f1H  = wa + 98304,  *f1L  = wa + 114688;
    u16 *f2H  = wa + 131072, *f2L  = wa + 139264;

    dim3 b(256);
    k_wcvt<<<dim3(64, 6), b, 0, stream>>>(sat_W, neigh_W, c1_W, c2_W, fc1_W, fc2_W, wa);
    k_xcvt<<<5000, b, 0, stream>>>(x, xH, xL, deg, counter);

    k_deg_count <<<2500, b, 0, stream>>>(e_dst, deg);
    k_assign    <<<157,  b, 0, stream>>>(deg, counter, start, cursor, csr);
    k_fill_edges<<<2500, b, 0, stream>>>(e_src, e_dst, cursor, csr);

    k_encoder<<<625, b, 0, stream>>>(xH, xL, satH, satL, neiH, neiL, sat_b, neigh_b, hH, hL);

    k_mfma_gemm<8, true, EPI_F32RAW><<<625, b, 0, stream>>>(
        hH, hL, c1H, c1L, nullptr, 128, hB, 128, nullptr, nullptr,
        c1_as, c1_ad, as_, ad_);
    k_aggregate<<<10000, b, 0, stream>>>(hB, as_, ad_, start, deg, csr, c1_b, hH, hL);

    k_mfma_gemm<8, true, EPI_F32RAW><<<625, b, 0, stream>>>(
        hH, hL, c2H, c2L, nullptr, 128, hB, 128, nullptr, nullptr,
        c2_as, c2_ad, as_, ad_);
    k_aggregate<<<10000, b, 0, stream>>>(hB, as_, ad_, start, deg, csr, c2_b, hH, hL);

    k_mfma_gemm<8, false, EPI_RELU_BF16><<<625, b, 0, stream>>>(
        hH, hL, f1H, f1L, fc1_b, 128, nullptr, 0, xH, xL,
        nullptr, nullptr, nullptr, nullptr);
    k_mfma_gemm<4, false, EPI_BIAS_F32><<<625, b, 0, stream>>>(
        xH, xL, f2H, f2L, fc2_b, 54, (float*)d_out, 54, nullptr, nullptr,
        nullptr, nullptr, nullptr, nullptr);
}

// Round 6
// 234.358 us; speedup vs baseline: 1.1374x; 1.1374x over previous
//
#include <hip/hip_runtime.h>

// Stage2GNN v6: v5 + bf16 gather in k_aggregate. Conv GEMMs write h as bf16
// (hi only) -> per-edge gather row 256B instead of 512B (the aggregate is
// L2/L3-bandwidth-bound: round-5 showed removing 40% of issue slots changed
// nothing). Alpha logits still computed from f32 accumulators in the GEMM
// epilogue, so only the weighted-average path carries bf16 rounding.

#define N_NODES 40000
#define N_EDGES 640000
#define DIM     128

typedef unsigned short u16;
typedef __attribute__((ext_vector_type(8))) short bf16x8;
typedef __attribute__((ext_vector_type(4))) float f32x4;

__device__ __forceinline__ u16 f2bf(float v) {
    unsigned u = __float_as_uint(v);
    u += 0x7FFFu + ((u >> 16) & 1u);
    return (u16)(u >> 16);
}
__device__ __forceinline__ float bf2f(u16 h) { return __uint_as_float(((unsigned)h) << 16); }
__device__ __forceinline__ float rdlane_f(float v, int l) {
    return __uint_as_float(__builtin_amdgcn_readlane(__float_as_uint(v), l));
}

// ---------------- input conversion + deg init ----------------
__global__ __launch_bounds__(256) void k_xcvt(const float* __restrict__ x,
                                              u16* __restrict__ xh, u16* __restrict__ xl,
                                              int* __restrict__ deg, int* __restrict__ counter) {
    int i = blockIdx.x * 256 + threadIdx.x;       // float4 index
    if (i < N_NODES) deg[i] = 1;                  // self loop
    if (i == 0) *counter = 0;
    const int n4 = N_NODES * DIM / 4;
    if (i >= n4) return;
    float4 v = ((const float4*)x)[i];
    u16 h0 = f2bf(v.x), h1 = f2bf(v.y), h2 = f2bf(v.z), h3 = f2bf(v.w);
    u16 l0 = f2bf(v.x - bf2f(h0)), l1 = f2bf(v.y - bf2f(h1));
    u16 l2 = f2bf(v.z - bf2f(h2)), l3 = f2bf(v.w - bf2f(h3));
    ((ushort4*)xh)[i] = make_ushort4(h0, h1, h2, h3);
    ((ushort4*)xl)[i] = make_ushort4(l0, l1, l2, l3);
}

__global__ __launch_bounds__(256) void k_wcvt(
    const float* __restrict__ satW, const float* __restrict__ neiW,
    const float* __restrict__ c1W, const float* __restrict__ c2W,
    const float* __restrict__ f1W, const float* __restrict__ f2W,
    u16* __restrict__ wa) {
    int m = blockIdx.y;
    const float* src; int C, K, Cp; int offH, offL;
    switch (m) {
        case 0: src = satW; C = 128; K = 64;  Cp = 128; offH = 0;      offL = 8192;   break;
        case 1: src = neiW; C = 128; K = 64;  Cp = 128; offH = 16384;  offL = 24576;  break;
        case 2: src = c1W;  C = 128; K = 128; Cp = 128; offH = 32768;  offL = 49152;  break;
        case 3: src = c2W;  C = 128; K = 128; Cp = 128; offH = 65536;  offL = 81920;  break;
        case 4: src = f1W;  C = 128; K = 128; Cp = 128; offH = 98304;  offL = 114688; break;
        default:src = f2W;  C = 54;  K = 128; Cp = 64;  offH = 131072; offL = 139264; break;
    }
    int e = blockIdx.x * 256 + threadIdx.x;
    if (e >= Cp * K) return;
    int c = e / K, k = e - c * K;
    float v = (c < C) ? src[c * K + k] : 0.f;
    u16 h = f2bf(v);
    wa[offH + e] = h;
    wa[offL + e] = f2bf(v - bf2f(h));
}

// ---------------- CSR build ----------------
__global__ void k_deg_count(const int* __restrict__ dst, int* __restrict__ deg) {
    int t = blockIdx.x * 256 + threadIdx.x;
    if (t < N_EDGES) atomicAdd(&deg[dst[t]], 1);
}
__global__ void k_assign(const int* __restrict__ deg, int* __restrict__ counter,
                         int* __restrict__ start, int* __restrict__ cursor,
                         int* __restrict__ csr_src) {
    int i = blockIdx.x * 256 + threadIdx.x;
    if (i >= N_NODES) return;
    int d = deg[i];
    int s = atomicAdd(counter, d);
    start[i] = s;
    csr_src[s] = i;
    cursor[i] = s + 1;
}
__global__ void k_fill_edges(const int* __restrict__ src, const int* __restrict__ dst,
                             int* __restrict__ cursor, int* __restrict__ csr_src) {
    int t = blockIdx.x * 256 + threadIdx.x;
    if (t < N_EDGES) {
        int p = atomicAdd(&cursor[dst[t]], 1);
        csr_src[p] = src[t];
    }
}

// ---------------- MFMA GEMM: out[r][c] = sum_k A[r][k]*W[c][k], K=128 ----------------
// Split bf16: acc += Ah*Wh + Ah*Wl + Al*Wh. BK=64 chunked W staging (32KB LDS).
enum { EPI_BF16H = 0, EPI_RELU_BF16 = 1, EPI_BIAS_F32 = 2 };

template<int CT, bool ALPHA, int EPI>
__global__ __launch_bounds__(256) void k_mfma_gemm(
    const u16* __restrict__ Ah, const u16* __restrict__ Al,
    const u16* __restrict__ Wh, const u16* __restrict__ Wl,
    const float* __restrict__ bias, int C,
    float* __restrict__ outF, int ldo,
    u16* __restrict__ outH, u16* __restrict__ outL,
    const float* __restrict__ a_src, const float* __restrict__ a_dst,
    float* __restrict__ as_, float* __restrict__ ad_)
{
    __shared__ u16 Ws[CT * 2 * 2 * 64 * 8];   // [ct][ks2][hilo2][lane64] x 8 u16
    const int tid = threadIdx.x;
    const int lane = tid & 63;
    const int wv = tid >> 6;
    const int r0 = blockIdx.x * 64 + wv * 16;
    const int arow = r0 + (lane & 15);
    const int kb = (lane >> 4) * 8;

    bf16x8 ah[4], al[4];
#pragma unroll
    for (int s = 0; s < 4; ++s) {
        ah[s] = *reinterpret_cast<const bf16x8*>(Ah + (size_t)arow * 128 + s * 32 + kb);
        al[s] = *reinterpret_cast<const bf16x8*>(Al + (size_t)arow * 128 + s * 32 + kb);
    }

    f32x4 acc[CT];
#pragma unroll
    for (int ct = 0; ct < CT; ++ct) acc[ct] = (f32x4){0.f, 0.f, 0.f, 0.f};

#pragma unroll
    for (int kc = 0; kc < 2; ++kc) {
        if (kc) __syncthreads();
        for (int idx = tid; idx < CT * 2 * 2 * 64; idx += 256) {
            int l = idx & 63;
            int q = idx >> 6;
            int hilo = q & 1;
            int ks = (q >> 1) & 1;
            int ct = q >> 2;
            int c = ct * 16 + (l & 15);
            int k = kc * 64 + ks * 32 + (l >> 4) * 8;
            const u16* Wp = hilo ? Wl : Wh;
            bf16x8 wv_ = *reinterpret_cast<const bf16x8*>(Wp + (size_t)c * 128 + k);
            *reinterpret_cast<bf16x8*>(&Ws[idx * 8]) = wv_;
        }
        __syncthreads();
#pragma unroll
        for (int ct = 0; ct < CT; ++ct) {
#pragma unroll
            for (int ks = 0; ks < 2; ++ks) {
                int s = kc * 2 + ks;
                int base = (ct * 2 + ks) * 1024;
                bf16x8 bh = *reinterpret_cast<const bf16x8*>(&Ws[base + lane * 8]);
                bf16x8 bl = *reinterpret_cast<const bf16x8*>(&Ws[base + 512 + lane * 8]);
                acc[ct] = __builtin_amdgcn_mfma_f32_16x16x32_bf16(ah[s], bh, acc[ct], 0, 0, 0);
                acc[ct] = __builtin_amdgcn_mfma_f32_16x16x32_bf16(ah[s], bl, acc[ct], 0, 0, 0);
                acc[ct] = __builtin_amdgcn_mfma_f32_16x16x32_bf16(al[s], bh, acc[ct], 0, 0, 0);
            }
        }
    }

    if constexpr (ALPHA) {
        float ps[4] = {0, 0, 0, 0}, pd[4] = {0, 0, 0, 0};
#pragma unroll
        for (int ct = 0; ct < CT; ++ct) {
            float asv = a_src[ct * 16 + (lane & 15)];
            float adv = a_dst[ct * 16 + (lane & 15)];
#pragma unroll
            for (int r = 0; r < 4; ++r) {
                ps[r] = fmaf(acc[ct][r], asv, ps[r]);
                pd[r] = fmaf(acc[ct][r], adv, pd[r]);
            }
        }
#pragma unroll
        for (int off = 1; off < 16; off <<= 1) {
#pragma unroll
            for (int r = 0; r < 4; ++r) {
                ps[r] += __shfl_xor(ps[r], off);
                pd[r] += __shfl_xor(pd[r], off);
            }
        }
        if ((lane & 15) == 0) {
#pragma unroll
            for (int r = 0; r < 4; ++r) {
                int row = r0 + (lane >> 4) * 4 + r;
                as_[row] = ps[r];
                ad_[row] = pd[r];
            }
        }
    }

#pragma unroll
    for (int ct = 0; ct < CT; ++ct) {
        int c = ct * 16 + (lane & 15);
#pragma unroll
        for (int r = 0; r < 4; ++r) {
            int row = r0 + (lane >> 4) * 4 + r;
            float v = acc[ct][r];
            if constexpr (EPI == EPI_BF16H) {
                outH[(size_t)row * 128 + c] = f2bf(v);   // bf16 h for gather
            } else if constexpr (EPI == EPI_RELU_BF16) {
                v = fmaxf(v + bias[c], 0.f);
                u16 h = f2bf(v);
                outH[(size_t)row * 128 + c] = h;
                outL[(size_t)row * 128 + c] = f2bf(v - bf2f(h));
            } else {
                if (c < C) outF[(size_t)row * ldo + c] = v + bias[c];
            }
        }
    }
}

// ---------------- fused encoder (two K=64 split-bf16 MFMA GEMMs, staged serially) ----------------
__global__ __launch_bounds__(256) void k_encoder(
    const u16* __restrict__ xh, const u16* __restrict__ xl,
    const u16* __restrict__ sH, const u16* __restrict__ sL,
    const u16* __restrict__ nH, const u16* __restrict__ nL,
    const float* __restrict__ satb, const float* __restrict__ neib,
    u16* __restrict__ outH, u16* __restrict__ outL)
{
    __shared__ u16 Ws[8 * 2 * 2 * 64 * 8];   // 32KB
    const int tid = threadIdx.x;
    const int lane = tid & 63;
    const int wv = tid >> 6;
    const int r0 = blockIdx.x * 64 + wv * 16;
    const int arow = r0 + (lane & 15);
    const int kb = (lane >> 4) * 8;

    bf16x8 axh[4], axl[4];
#pragma unroll
    for (int s = 0; s < 4; ++s) {
        axh[s] = *reinterpret_cast<const bf16x8*>(xh + (size_t)arow * 128 + s * 32 + kb);
        axl[s] = *reinterpret_cast<const bf16x8*>(xl + (size_t)arow * 128 + s * 32 + kb);
    }

    f32x4 accS[8], accN[8];
#pragma unroll
    for (int ct = 0; ct < 8; ++ct) { accS[ct] = (f32x4){0,0,0,0}; accN[ct] = (f32x4){0,0,0,0}; }

#pragma unroll
    for (int mat = 0; mat < 2; ++mat) {
        if (mat) __syncthreads();
        const u16* WH = mat ? nH : sH;
        const u16* WL = mat ? nL : sL;
        for (int idx = tid; idx < 2048; idx += 256) {
            int l = idx & 63;
            int q = idx >> 6;
            int hilo = q & 1;
            int ks = (q >> 1) & 1;
            int ct = q >> 2;
            int c = ct * 16 + (l & 15);
            int k = ks * 32 + (l >> 4) * 8;
            const u16* Wp = hilo ? WL : WH;
            bf16x8 wv_ = *reinterpret_cast<const bf16x8*>(Wp + (size_t)c * 64 + k);
            *reinterpret_cast<bf16x8*>(&Ws[idx * 8]) = wv_;
        }
        __syncthreads();
#pragma unroll
        for (int ct = 0; ct < 8; ++ct) {
#pragma unroll
            for (int ks = 0; ks < 2; ++ks) {
                int s = mat * 2 + ks;    // sat: x slices 0-1; nei: x slices 2-3
                int base = (ct * 2 + ks) * 1024;
                bf16x8 bh = *reinterpret_cast<const bf16x8*>(&Ws[base + lane * 8]);
                bf16x8 bl = *reinterpret_cast<const bf16x8*>(&Ws[base + 512 + lane * 8]);
                f32x4* ac = mat ? &accN[ct] : &accS[ct];
                *ac = __builtin_amdgcn_mfma_f32_16x16x32_bf16(axh[s], bh, *ac, 0, 0, 0);
                *ac = __builtin_amdgcn_mfma_f32_16x16x32_bf16(axh[s], bl, *ac, 0, 0, 0);
                *ac = __builtin_amdgcn_mfma_f32_16x16x32_bf16(axl[s], bh, *ac, 0, 0, 0);
            }
        }
    }

#pragma unroll
    for (int ct = 0; ct < 8; ++ct) {
        int c = ct * 16 + (lane & 15);
        float bs = satb[c], bn = neib[c];
#pragma unroll
        for (int r = 0; r < 4; ++r) {
            int row = r0 + (lane >> 4) * 4 + r;
            float v = fmaxf(accS[ct][r] + bs, 0.f) + 0.5f * fmaxf(accN[ct][r] + bn, 0.f);
            u16 h = f2bf(v);
            outH[(size_t)row * 128 + c] = h;
            outL[(size_t)row * 128 + c] = f2bf(v - bf2f(h));
        }
    }
}

// ---------------- wave-per-node softmax + aggregation (bf16 gather) ----------------
// 2 edge-rows per wave-op (lanes 0-31 even edge, 32-63 odd edge, 4 dims each
// as ushort4 = 8B). Degree-adaptive tail (8/4/2/1-pair bodies).
#define DO_PAIRS(NP, TB)                                                      \
    {                                                                         \
        float pw[NP]; const ushort4* hp[NP];                                  \
        _Pragma("unroll")                                                     \
        for (int q = 0; q < NP; ++q) {                                        \
            int e0 = (TB) + 2 * q;                                            \
            float plo = rdlane_f(p, e0), phi = rdlane_f(p, e0 + 1);           \
            int jlo = __builtin_amdgcn_readlane(jj, e0);                      \
            int jhi = __builtin_amdgcn_readlane(jj, e0 + 1);                  \
            pw[q] = hodd ? phi : plo;                                         \
            int j = hodd ? jhi : jlo;                                         \
            hp[q] = (const ushort4*)&hg[(size_t)j * 128 + 4 * l32];           \
        }                                                                     \
        ushort4 hv[NP];                                                       \
        _Pragma("unroll") for (int q = 0; q < NP; ++q) hv[q] = *hp[q];        \
        _Pragma("unroll") for (int q = 0; q < NP; ++q) {                      \
            acc.x = fmaf(pw[q], bf2f(hv[q].x), acc.x);                        \
            acc.y = fmaf(pw[q], bf2f(hv[q].y), acc.y);                        \
            acc.z = fmaf(pw[q], bf2f(hv[q].z), acc.z);                        \
            acc.w = fmaf(pw[q], bf2f(hv[q].w), acc.w);                        \
        }                                                                     \
    }

__global__ __launch_bounds__(256) void k_aggregate(
    const u16* __restrict__ hg, const float* __restrict__ as_,
    const float* __restrict__ ad_, const int* __restrict__ start,
    const int* __restrict__ deg, const int* __restrict__ csr_src,
    const float* __restrict__ bias, u16* __restrict__ outH, u16* __restrict__ outL)
{
    int wid = (blockIdx.x * 256 + threadIdx.x) >> 6;
    int lane = threadIdx.x & 63;
    if (wid >= N_NODES) return;

    const int s0 = start[wid];
    const int s1 = s0 + deg[wid];
    const float adi = ad_[wid];
    const int l32 = lane & 31;
    const bool hodd = lane >= 32;

    float4 acc = make_float4(0.f, 0.f, 0.f, 0.f);
    float ssum = 0.f;
    for (int base = s0; base < s1; base += 64) {
        int k = base + lane;
        int cnt = min(64, s1 - base);   // wave-uniform
        int jj = 0;
        float p = 0.f;
        if (k < s1) {
            jj = csr_src[k];
            float e = as_[jj] + adi;
            e = (e > 0.f) ? e : 0.2f * e;
            p = __expf(e);              // |e| << 88: no max-shift needed
            ssum += p;
        }
        int t = 0;
        for (; t + 16 <= cnt; t += 16) DO_PAIRS(8, t)
        if (t + 8 <= cnt) { DO_PAIRS(4, t) t += 8; }
        if (t + 4 <= cnt) { DO_PAIRS(2, t) t += 4; }
        for (; t < cnt; t += 2) DO_PAIRS(1, t)   // final pair may hold 1 dummy
    }
#pragma unroll
    for (int off = 32; off; off >>= 1) ssum += __shfl_xor(ssum, off);
    acc.x += __shfl_xor(acc.x, 32);
    acc.y += __shfl_xor(acc.y, 32);
    acc.z += __shfl_xor(acc.z, 32);
    acc.w += __shfl_xor(acc.w, 32);
    float inv = 1.f / (ssum + 1e-16f);

    if (!hodd) {
        float4 bv = *(const float4*)&bias[4 * l32];
        float o0 = fmaxf(fmaf(acc.x, inv, bv.x), 0.f);
        float o1 = fmaxf(fmaf(acc.y, inv, bv.y), 0.f);
        float o2 = fmaxf(fmaf(acc.z, inv, bv.z), 0.f);
        float o3 = fmaxf(fmaf(acc.w, inv, bv.w), 0.f);
        u16 h0 = f2bf(o0), h1 = f2bf(o1), h2 = f2bf(o2), h3 = f2bf(o3);
        ushort4 hvv = make_ushort4(h0, h1, h2, h3);
        ushort4 lvv = make_ushort4(f2bf(o0 - bf2f(h0)), f2bf(o1 - bf2f(h1)),
                                   f2bf(o2 - bf2f(h2)), f2bf(o3 - bf2f(h3)));
        *(ushort4*)&outH[(size_t)wid * 128 + 4 * l32] = hvv;
        *(ushort4*)&outL[(size_t)wid * 128 + 4 * l32] = lvv;
    }
}

extern "C" void kernel_launch(void* const* d_in, const int* in_sizes, int n_in,
                              void* d_out, int out_size, void* d_ws, size_t ws_size,
                              hipStream_t stream) {
    (void)in_sizes; (void)n_in; (void)out_size; (void)ws_size;

    const float* x       = (const float*)d_in[0];
    const int*   ei      = (const int*)d_in[1];
    const float* sat_W   = (const float*)d_in[2];
    const float* sat_b   = (const float*)d_in[3];
    const float* neigh_W = (const float*)d_in[4];
    const float* neigh_b = (const float*)d_in[5];
    const float* c1_W    = (const float*)d_in[6];
    const float* c1_as   = (const float*)d_in[7];
    const float* c1_ad   = (const float*)d_in[8];
    const float* c1_b    = (const float*)d_in[9];
    const float* c2_W    = (const float*)d_in[10];
    const float* c2_as   = (const float*)d_in[11];
    const float* c2_ad   = (const float*)d_in[12];
    const float* c2_b    = (const float*)d_in[13];
    const float* fc1_W   = (const float*)d_in[14];
    const float* fc1_b   = (const float*)d_in[15];
    const float* fc2_W   = (const float*)d_in[16];
    const float* fc2_b   = (const float*)d_in[17];

    const int* e_src = ei;
    const int* e_dst = ei + N_EDGES;

    char* w = (char*)d_ws;
    u16*   hG     = (u16*)  (w);                  // [N,128] bf16 h (gather)
    u16*   xH     = (u16*)  (w + 20480000);
    u16*   xL     = (u16*)  (w + 30720000);
    u16*   hH     = (u16*)  (w + 40960000);
    u16*   hL     = (u16*)  (w + 51200000);
    float* as_    = (float*)(w + 61440000);
    float* ad_    = (float*)(w + 61600000);
    int*   deg    = (int*)  (w + 61760000);
    int*   start  = (int*)  (w + 61920000);
    int*   cursor = (int*)  (w + 62080000);
    int*   counter= (int*)  (w + 62240000);
    int*   csr    = (int*)  (w + 62240256);
    u16*   wa     = (u16*)  (w + 64960512);

    u16 *satH = wa,          *satL = wa + 8192;
    u16 *neiH = wa + 16384,  *neiL = wa + 24576;
    u16 *c1H  = wa + 32768,  *c1L  = wa + 49152;
    u16 *c2H  = wa + 65536,  *c2L  = wa + 81920;
    u16 *f1H  = wa + 98304,  *f1L  = wa + 114688;
    u16 *f2H  = wa + 131072, *f2L  = wa + 139264;

    dim3 b(256);
    k_wcvt<<<dim3(64, 6), b, 0, stream>>>(sat_W, neigh_W, c1_W, c2_W, fc1_W, fc2_W, wa);
    k_xcvt<<<5000, b, 0, stream>>>(x, xH, xL, deg, counter);

    k_deg_count <<<2500, b, 0, stream>>>(e_dst, deg);
    k_assign    <<<157,  b, 0, stream>>>(deg, counter, start, cursor, csr);
    k_fill_edges<<<2500, b, 0, stream>>>(e_src, e_dst, cursor, csr);

    k_encoder<<<625, b, 0, stream>>>(xH, xL, satH, satL, neiH, neiL, sat_b, neigh_b, hH, hL);

    k_mfma_gemm<8, true, EPI_BF16H><<<625, b, 0, stream>>>(
        hH, hL, c1H, c1L, nullptr, 128, nullptr, 0, hG, nullptr,
        c1_as, c1_ad, as_, ad_);
    k_aggregate<<<10000, b, 0, stream>>>(hG, as_, ad_, start, deg, csr, c1_b, hH, hL);

    k_mfma_gemm<8, true, EPI_BF16H><<<625, b, 0, stream>>>(
        hH, hL, c2H, c2L, nullptr, 128, nullptr, 0, hG, nullptr,
        c2_as, c2_ad, as_, ad_);
    k_aggregate<<<10000, b, 0, stream>>>(hG, as_, ad_, start, deg, csr, c2_b, hH, hL);

    k_mfma_gemm<8, false, EPI_RELU_BF16><<<625, b, 0, stream>>>(
        hH, hL, f1H, f1L, fc1_b, 128, nullptr, 0, xH, xL,
        nullptr, nullptr, nullptr, nullptr);
    k_mfma_gemm<4, false, EPI_BIAS_F32><<<625, b, 0, stream>>>(
        xH, xL, f2H, f2L, fc2_b, 54, (float*)d_out, 54, nullptr, nullptr,
        nullptr, nullptr, nullptr, nullptr);
}

// Round 7
// 213.303 us; speedup vs baseline: 1.2497x; 1.0987x over previous
//
#include <hip/hip_runtime.h>

// Stage2GNN v7: v6 + fusion. 9 kernels:
//   wcvt(+deg init), deg_count, assign, fill_edges,
//   enc_conv1 (x->encoder->LDS h->conv1 GEMM + alpha), agg1,
//   conv2 GEMM (+alpha), agg2, fc12 (fc1->LDS h'->fc2).
// Encoder h and fc1 h' never touch global (swizzled f32 LDS staging).
// Numerics identical to v6 (same f2bf split points) -> absmax 0.00390625.

#define N_NODES 40000
#define N_EDGES 640000
#define DIM     128

typedef unsigned short u16;
typedef __attribute__((ext_vector_type(8))) short bf16x8;
typedef __attribute__((ext_vector_type(4))) float f32x4;

__device__ __forceinline__ u16 f2bf(float v) {
    unsigned u = __float_as_uint(v);
    u += 0x7FFFu + ((u >> 16) & 1u);
    return (u16)(u >> 16);
}
__device__ __forceinline__ float bf2f(u16 h) { return __uint_as_float(((unsigned)h) << 16); }
__device__ __forceinline__ float rdlane_f(float v, int l) {
    return __uint_as_float(__builtin_amdgcn_readlane(__float_as_uint(v), l));
}

// swizzled f32 LDS tile [64][128]: 4-f32 block b of row r stored at b^(r&7)
__device__ __forceinline__ int hswz(int row, int col) {
    return row * 128 + ((((col >> 2) ^ (row & 7))) << 2) + (col & 3);
}
__device__ __forceinline__ float4 hread4(const float* hbuf, int row, int k) {  // k mult of 4
    int b = (k >> 2) ^ (row & 7);
    return *(const float4*)&hbuf[row * 128 + (b << 2)];
}
__device__ __forceinline__ void split8(const float* vv, bf16x8& hi, bf16x8& lo) {
#pragma unroll
    for (int i = 0; i < 8; ++i) {
        u16 h = f2bf(vv[i]);
        hi[i] = (short)h;
        lo[i] = (short)f2bf(vv[i] - bf2f(h));
    }
}

// ---------------- weight conversion + deg/counter init ----------------
__global__ __launch_bounds__(256) void k_wcvt(
    const float* __restrict__ satW, const float* __restrict__ neiW,
    const float* __restrict__ c1W, const float* __restrict__ c2W,
    const float* __restrict__ f1W, const float* __restrict__ f2W,
    u16* __restrict__ wa, int* __restrict__ deg, int* __restrict__ counter) {
    int gid = (blockIdx.y * gridDim.x + blockIdx.x) * 256 + threadIdx.x;
    if (gid < N_NODES) deg[gid] = 1;   // self loop
    if (gid == 0) *counter = 0;

    int m = blockIdx.y;
    const float* src; int C, K, Cp; int offH, offL;
    switch (m) {
        case 0: src = satW; C = 128; K = 64;  Cp = 128; offH = 0;      offL = 8192;   break;
        case 1: src = neiW; C = 128; K = 64;  Cp = 128; offH = 16384;  offL = 24576;  break;
        case 2: src = c1W;  C = 128; K = 128; Cp = 128; offH = 32768;  offL = 49152;  break;
        case 3: src = c2W;  C = 128; K = 128; Cp = 128; offH = 65536;  offL = 81920;  break;
        case 4: src = f1W;  C = 128; K = 128; Cp = 128; offH = 98304;  offL = 114688; break;
        default:src = f2W;  C = 54;  K = 128; Cp = 64;  offH = 131072; offL = 139264; break;
    }
    int e = blockIdx.x * 256 + threadIdx.x;
    if (e >= Cp * K) return;
    int c = e / K, k = e - c * K;
    float v = (c < C) ? src[c * K + k] : 0.f;
    u16 h = f2bf(v);
    wa[offH + e] = h;
    wa[offL + e] = f2bf(v - bf2f(h));
}

// ---------------- CSR build ----------------
__global__ void k_deg_count(const int* __restrict__ dst, int* __restrict__ deg) {
    int t = blockIdx.x * 256 + threadIdx.x;
    if (t < N_EDGES) atomicAdd(&deg[dst[t]], 1);
}
__global__ void k_assign(const int* __restrict__ deg, int* __restrict__ counter,
                         int* __restrict__ start, int* __restrict__ cursor,
                         int* __restrict__ csr_src) {
    int i = blockIdx.x * 256 + threadIdx.x;
    if (i >= N_NODES) return;
    int d = deg[i];
    int s = atomicAdd(counter, d);
    start[i] = s;
    csr_src[s] = i;
    cursor[i] = s + 1;
}
__global__ void k_fill_edges(const int* __restrict__ src, const int* __restrict__ dst,
                             int* __restrict__ cursor, int* __restrict__ csr_src) {
    int t = blockIdx.x * 256 + threadIdx.x;
    if (t < N_EDGES) {
        int p = atomicAdd(&cursor[dst[t]], 1);
        csr_src[p] = src[t];
    }
}

// ---------------- shared GEMM pieces ----------------
// W staging into LDS fragment order (v6-proven): idx = [ct][ks2][hilo2][lane64]
template<int CT>
__device__ __forceinline__ void stage_W(u16* Ws, const u16* __restrict__ Wh,
                                        const u16* __restrict__ Wl, int kc, int tid) {
    for (int idx = tid; idx < CT * 2 * 2 * 64; idx += 256) {
        int l = idx & 63;
        int q = idx >> 6;
        int hilo = q & 1;
        int ks = (q >> 1) & 1;
        int ct = q >> 2;
        int c = ct * 16 + (l & 15);
        int k = kc * 64 + ks * 32 + (l >> 4) * 8;
        const u16* Wp = hilo ? Wl : Wh;
        *reinterpret_cast<bf16x8*>(&Ws[idx * 8]) =
            *reinterpret_cast<const bf16x8*>(Wp + (size_t)c * 128 + k);
    }
}

#define MFMA3(ACC, AH, AL, BH, BL)                                             \
    ACC = __builtin_amdgcn_mfma_f32_16x16x32_bf16(AH, BH, ACC, 0, 0, 0);       \
    ACC = __builtin_amdgcn_mfma_f32_16x16x32_bf16(AH, BL, ACC, 0, 0, 0);       \
    ACC = __builtin_amdgcn_mfma_f32_16x16x32_bf16(AL, BH, ACC, 0, 0, 0);

// alpha epilogue: as_/ad_ from f32 accumulators
__device__ __forceinline__ void alpha_epi(const f32x4* acc, int lane, int r0,
                                          const float* __restrict__ a_src,
                                          const float* __restrict__ a_dst,
                                          float* __restrict__ as_, float* __restrict__ ad_) {
    float ps[4] = {0, 0, 0, 0}, pd[4] = {0, 0, 0, 0};
#pragma unroll
    for (int ct = 0; ct < 8; ++ct) {
        float asv = a_src[ct * 16 + (lane & 15)];
        float adv = a_dst[ct * 16 + (lane & 15)];
#pragma unroll
        for (int r = 0; r < 4; ++r) {
            ps[r] = fmaf(acc[ct][r], asv, ps[r]);
            pd[r] = fmaf(acc[ct][r], adv, pd[r]);
        }
    }
#pragma unroll
    for (int off = 1; off < 16; off <<= 1) {
#pragma unroll
        for (int r = 0; r < 4; ++r) {
            ps[r] += __shfl_xor(ps[r], off);
            pd[r] += __shfl_xor(pd[r], off);
        }
    }
    if ((lane & 15) == 0) {
#pragma unroll
        for (int r = 0; r < 4; ++r) {
            int row = r0 + (lane >> 4) * 4 + r;
            as_[row] = ps[r];
            ad_[row] = pd[r];
        }
    }
}

// ---------------- fused encoder + conv1 GEMM ----------------
__global__ __launch_bounds__(256) void k_enc_conv1(
    const float* __restrict__ x,
    const u16* __restrict__ sH, const u16* __restrict__ sL,
    const u16* __restrict__ nH, const u16* __restrict__ nL,
    const float* __restrict__ satb, const float* __restrict__ neib,
    const u16* __restrict__ Wh, const u16* __restrict__ Wl,   // conv1
    const float* __restrict__ a_src, const float* __restrict__ a_dst,
    u16* __restrict__ outG, float* __restrict__ as_, float* __restrict__ ad_)
{
    __shared__ u16 Wbuf[16384];    // 32KB
    __shared__ float hbuf[8192];   // 32KB
    const int tid = threadIdx.x, lane = tid & 63, wv = tid >> 6;
    const int r0 = blockIdx.x * 64 + wv * 16;
    const int arow = r0 + (lane & 15);
    const int kb = (lane >> 4) * 8;

    // x fragments: f32 -> split bf16 in registers
    bf16x8 axh[4], axl[4];
#pragma unroll
    for (int s = 0; s < 4; ++s) {
        const float* p = x + (size_t)arow * 128 + s * 32 + kb;
        float4 a = *(const float4*)p;
        float4 b = *(const float4*)(p + 4);
        float vv[8] = {a.x, a.y, a.z, a.w, b.x, b.y, b.z, b.w};
        split8(vv, axh[s], axl[s]);
    }

    f32x4 accS[8], accN[8];
#pragma unroll
    for (int ct = 0; ct < 8; ++ct) { accS[ct] = (f32x4){0,0,0,0}; accN[ct] = (f32x4){0,0,0,0}; }

    // encoder: sat (x cols 0-63), nei (x cols 64-127); K=64 each
#pragma unroll
    for (int mat = 0; mat < 2; ++mat) {
        if (mat) __syncthreads();
        const u16* WH = mat ? nH : sH;
        const u16* WL = mat ? nL : sL;
        for (int idx = tid; idx < 2048; idx += 256) {
            int l = idx & 63;
            int q = idx >> 6;
            int hilo = q & 1;
            int ks = (q >> 1) & 1;
            int ct = q >> 2;
            int c = ct * 16 + (l & 15);
            int k = ks * 32 + (l >> 4) * 8;
            const u16* Wp = hilo ? WL : WH;
            *reinterpret_cast<bf16x8*>(&Wbuf[idx * 8]) =
                *reinterpret_cast<const bf16x8*>(Wp + (size_t)c * 64 + k);
        }
        __syncthreads();
#pragma unroll
        for (int ct = 0; ct < 8; ++ct) {
#pragma unroll
            for (int ks = 0; ks < 2; ++ks) {
                int s = mat * 2 + ks;
                int base = (ct * 2 + ks) * 1024;
                bf16x8 bh = *reinterpret_cast<const bf16x8*>(&Wbuf[base + lane * 8]);
                bf16x8 bl = *reinterpret_cast<const bf16x8*>(&Wbuf[base + 512 + lane * 8]);
                f32x4* ac = mat ? &accN[ct] : &accS[ct];
                MFMA3((*ac), axh[s], axl[s], bh, bl);
            }
        }
    }

    // h -> LDS (f32, swizzled)
#pragma unroll
    for (int ct = 0; ct < 8; ++ct) {
        int c = ct * 16 + (lane & 15);
        float bs = satb[c], bn = neib[c];
#pragma unroll
        for (int r = 0; r < 4; ++r) {
            int rl = wv * 16 + (lane >> 4) * 4 + r;
            float v = fmaxf(accS[ct][r] + bs, 0.f) + 0.5f * fmaxf(accN[ct][r] + bn, 0.f);
            hbuf[hswz(rl, c)] = v;
        }
    }
    __syncthreads();

    // conv1 A fragments from LDS
    bf16x8 ah[4], al[4];
    const int ar = wv * 16 + (lane & 15);
#pragma unroll
    for (int s = 0; s < 4; ++s) {
        int k0 = s * 32 + kb;
        float4 a = hread4(hbuf, ar, k0);
        float4 b = hread4(hbuf, ar, k0 + 4);
        float vv[8] = {a.x, a.y, a.z, a.w, b.x, b.y, b.z, b.w};
        split8(vv, ah[s], al[s]);
    }

    f32x4 acc[8];
#pragma unroll
    for (int ct = 0; ct < 8; ++ct) acc[ct] = (f32x4){0, 0, 0, 0};
#pragma unroll
    for (int kc = 0; kc < 2; ++kc) {
        if (kc) __syncthreads();
        stage_W<8>(Wbuf, Wh, Wl, kc, tid);
        __syncthreads();
#pragma unroll
        for (int ct = 0; ct < 8; ++ct) {
#pragma unroll
            for (int ks = 0; ks < 2; ++ks) {
                int s = kc * 2 + ks;
                int base = (ct * 2 + ks) * 1024;
                bf16x8 bh = *reinterpret_cast<const bf16x8*>(&Wbuf[base + lane * 8]);
                bf16x8 bl = *reinterpret_cast<const bf16x8*>(&Wbuf[base + 512 + lane * 8]);
                MFMA3(acc[ct], ah[s], al[s], bh, bl);
            }
        }
    }

    alpha_epi(acc, lane, r0, a_src, a_dst, as_, ad_);

#pragma unroll
    for (int ct = 0; ct < 8; ++ct) {
        int c = ct * 16 + (lane & 15);
#pragma unroll
        for (int r = 0; r < 4; ++r) {
            int row = r0 + (lane >> 4) * 4 + r;
            outG[(size_t)row * 128 + c] = f2bf(acc[ct][r]);
        }
    }
}

// ---------------- conv2 GEMM (+alpha), A from global hi/lo ----------------
__global__ __launch_bounds__(256) void k_conv_gemm(
    const u16* __restrict__ Ah, const u16* __restrict__ Al,
    const u16* __restrict__ Wh, const u16* __restrict__ Wl,
    const float* __restrict__ a_src, const float* __restrict__ a_dst,
    u16* __restrict__ outG, float* __restrict__ as_, float* __restrict__ ad_)
{
    __shared__ u16 Wbuf[16384];
    const int tid = threadIdx.x, lane = tid & 63, wv = tid >> 6;
    const int r0 = blockIdx.x * 64 + wv * 16;
    const int arow = r0 + (lane & 15);
    const int kb = (lane >> 4) * 8;

    bf16x8 ah[4], al[4];
#pragma unroll
    for (int s = 0; s < 4; ++s) {
        ah[s] = *reinterpret_cast<const bf16x8*>(Ah + (size_t)arow * 128 + s * 32 + kb);
        al[s] = *reinterpret_cast<const bf16x8*>(Al + (size_t)arow * 128 + s * 32 + kb);
    }

    f32x4 acc[8];
#pragma unroll
    for (int ct = 0; ct < 8; ++ct) acc[ct] = (f32x4){0, 0, 0, 0};
#pragma unroll
    for (int kc = 0; kc < 2; ++kc) {
        if (kc) __syncthreads();
        stage_W<8>(Wbuf, Wh, Wl, kc, tid);
        __syncthreads();
#pragma unroll
        for (int ct = 0; ct < 8; ++ct) {
#pragma unroll
            for (int ks = 0; ks < 2; ++ks) {
                int s = kc * 2 + ks;
                int base = (ct * 2 + ks) * 1024;
                bf16x8 bh = *reinterpret_cast<const bf16x8*>(&Wbuf[base + lane * 8]);
                bf16x8 bl = *reinterpret_cast<const bf16x8*>(&Wbuf[base + 512 + lane * 8]);
                MFMA3(acc[ct], ah[s], al[s], bh, bl);
            }
        }
    }

    alpha_epi(acc, lane, r0, a_src, a_dst, as_, ad_);

#pragma unroll
    for (int ct = 0; ct < 8; ++ct) {
        int c = ct * 16 + (lane & 15);
#pragma unroll
        for (int r = 0; r < 4; ++r) {
            int row = r0 + (lane >> 4) * 4 + r;
            outG[(size_t)row * 128 + c] = f2bf(acc[ct][r]);
        }
    }
}

// ---------------- fused fc1 + fc2 ----------------
__global__ __launch_bounds__(256) void k_fc12(
    const u16* __restrict__ Ah, const u16* __restrict__ Al,
    const u16* __restrict__ W1h, const u16* __restrict__ W1l, const float* __restrict__ b1,
    const u16* __restrict__ W2h, const u16* __restrict__ W2l, const float* __restrict__ b2,
    float* __restrict__ out)
{
    __shared__ u16 Wbuf[16384];    // 32KB; reused as f32 h' tile after fc1
    __shared__ u16 W2buf[8192];    // 16KB
    float* hbuf = (float*)Wbuf;
    const int tid = threadIdx.x, lane = tid & 63, wv = tid >> 6;
    const int r0 = blockIdx.x * 64 + wv * 16;
    const int arow = r0 + (lane & 15);
    const int kb = (lane >> 4) * 8;

    bf16x8 ah[4], al[4];
#pragma unroll
    for (int s = 0; s < 4; ++s) {
        ah[s] = *reinterpret_cast<const bf16x8*>(Ah + (size_t)arow * 128 + s * 32 + kb);
        al[s] = *reinterpret_cast<const bf16x8*>(Al + (size_t)arow * 128 + s * 32 + kb);
    }

    f32x4 acc[8];
#pragma unroll
    for (int ct = 0; ct < 8; ++ct) acc[ct] = (f32x4){0, 0, 0, 0};
#pragma unroll
    for (int kc = 0; kc < 2; ++kc) {
        if (kc) __syncthreads();
        stage_W<8>(Wbuf, W1h, W1l, kc, tid);
        __syncthreads();
#pragma unroll
        for (int ct = 0; ct < 8; ++ct) {
#pragma unroll
            for (int ks = 0; ks < 2; ++ks) {
                int s = kc * 2 + ks;
                int base = (ct * 2 + ks) * 1024;
                bf16x8 bh = *reinterpret_cast<const bf16x8*>(&Wbuf[base + lane * 8]);
                bf16x8 bl = *reinterpret_cast<const bf16x8*>(&Wbuf[base + 512 + lane * 8]);
                MFMA3(acc[ct], ah[s], al[s], bh, bl);
            }
        }
    }
    __syncthreads();   // all waves done reading Wbuf

    // h' = relu(fc1 + b1) -> LDS f32 (overlays Wbuf)
#pragma unroll
    for (int ct = 0; ct < 8; ++ct) {
        int c = ct * 16 + (lane & 15);
        float bv = b1[c];
#pragma unroll
        for (int r = 0; r < 4; ++r) {
            int rl = wv * 16 + (lane >> 4) * 4 + r;
            hbuf[hswz(rl, c)] = fmaxf(acc[ct][r] + bv, 0.f);
        }
    }
    __syncthreads();

    // fc2 A fragments from LDS
    bf16x8 a2h[4], a2l[4];
    const int ar = wv * 16 + (lane & 15);
#pragma unroll
    for (int s = 0; s < 4; ++s) {
        int k0 = s * 32 + kb;
        float4 a = hread4(hbuf, ar, k0);
        float4 b = hread4(hbuf, ar, k0 + 4);
        float vv[8] = {a.x, a.y, a.z, a.w, b.x, b.y, b.z, b.w};
        split8(vv, a2h[s], a2l[s]);
    }

    f32x4 acc2[4];
#pragma unroll
    for (int ct = 0; ct < 4; ++ct) acc2[ct] = (f32x4){0, 0, 0, 0};
#pragma unroll
    for (int kc = 0; kc < 2; ++kc) {
        if (kc) __syncthreads();
        stage_W<4>(W2buf, W2h, W2l, kc, tid);
        __syncthreads();
#pragma unroll
        for (int ct = 0; ct < 4; ++ct) {
#pragma unroll
            for (int ks = 0; ks < 2; ++ks) {
                int s = kc * 2 + ks;
                int base = (ct * 2 + ks) * 1024;
                bf16x8 bh = *reinterpret_cast<const bf16x8*>(&W2buf[base + lane * 8]);
                bf16x8 bl = *reinterpret_cast<const bf16x8*>(&W2buf[base + 512 + lane * 8]);
                MFMA3(acc2[ct], a2h[s], a2l[s], bh, bl);
            }
        }
    }

#pragma unroll
    for (int ct = 0; ct < 4; ++ct) {
        int c = ct * 16 + (lane & 15);
#pragma unroll
        for (int r = 0; r < 4; ++r) {
            int row = r0 + (lane >> 4) * 4 + r;
            if (c < 54) out[(size_t)row * 54 + c] = acc2[ct][r] + b2[c];
        }
    }
}

// ---------------- wave-per-node softmax + aggregation (bf16 gather) ----------------
#define DO_PAIRS(NP, TB)                                                      \
    {                                                                         \
        float pw[NP]; const ushort4* hp[NP];                                  \
        _Pragma("unroll")                                                     \
        for (int q = 0; q < NP; ++q) {                                        \
            int e0 = (TB) + 2 * q;                                            \
            float plo = rdlane_f(p, e0), phi = rdlane_f(p, e0 + 1);           \
            int jlo = __builtin_amdgcn_readlane(jj, e0);                      \
            int jhi = __builtin_amdgcn_readlane(jj, e0 + 1);                  \
            pw[q] = hodd ? phi : plo;                                         \
            int j = hodd ? jhi : jlo;                                         \
            hp[q] = (const ushort4*)&hg[(size_t)j * 128 + 4 * l32];           \
        }                                                                     \
        ushort4 hv[NP];                                                       \
        _Pragma("unroll") for (int q = 0; q < NP; ++q) hv[q] = *hp[q];        \
        _Pragma("unroll") for (int q = 0; q < NP; ++q) {                      \
            acc.x = fmaf(pw[q], bf2f(hv[q].x), acc.x);                        \
            acc.y = fmaf(pw[q], bf2f(hv[q].y), acc.y);                        \
            acc.z = fmaf(pw[q], bf2f(hv[q].z), acc.z);                        \
            acc.w = fmaf(pw[q], bf2f(hv[q].w), acc.w);                        \
        }                                                                     \
    }

__global__ __launch_bounds__(256) void k_aggregate(
    const u16* __restrict__ hg, const float* __restrict__ as_,
    const float* __restrict__ ad_, const int* __restrict__ start,
    const int* __restrict__ deg, const int* __restrict__ csr_src,
    const float* __restrict__ bias, u16* __restrict__ outH, u16* __restrict__ outL)
{
    int wid = (blockIdx.x * 256 + threadIdx.x) >> 6;
    int lane = threadIdx.x & 63;
    if (wid >= N_NODES) return;

    const int s0 = start[wid];
    const int s1 = s0 + deg[wid];
    const float adi = ad_[wid];
    const int l32 = lane & 31;
    const bool hodd = lane >= 32;

    float4 acc = make_float4(0.f, 0.f, 0.f, 0.f);
    float ssum = 0.f;
    for (int base = s0; base < s1; base += 64) {
        int k = base + lane;
        int cnt = min(64, s1 - base);   // wave-uniform
        int jj = 0;
        float p = 0.f;
        if (k < s1) {
            jj = csr_src[k];
            float e = as_[jj] + adi;
            e = (e > 0.f) ? e : 0.2f * e;
            p = __expf(e);              // |e| << 88: no max-shift needed
            ssum += p;
        }
        int t = 0;
        for (; t + 16 <= cnt; t += 16) DO_PAIRS(8, t)
        if (t + 8 <= cnt) { DO_PAIRS(4, t) t += 8; }
        if (t + 4 <= cnt) { DO_PAIRS(2, t) t += 4; }
        for (; t < cnt; t += 2) DO_PAIRS(1, t)
    }
#pragma unroll
    for (int off = 32; off; off >>= 1) ssum += __shfl_xor(ssum, off);
    acc.x += __shfl_xor(acc.x, 32);
    acc.y += __shfl_xor(acc.y, 32);
    acc.z += __shfl_xor(acc.z, 32);
    acc.w += __shfl_xor(acc.w, 32);
    float inv = 1.f / (ssum + 1e-16f);

    if (!hodd) {
        float4 bv = *(const float4*)&bias[4 * l32];
        float o0 = fmaxf(fmaf(acc.x, inv, bv.x), 0.f);
        float o1 = fmaxf(fmaf(acc.y, inv, bv.y), 0.f);
        float o2 = fmaxf(fmaf(acc.z, inv, bv.z), 0.f);
        float o3 = fmaxf(fmaf(acc.w, inv, bv.w), 0.f);
        u16 h0 = f2bf(o0), h1 = f2bf(o1), h2 = f2bf(o2), h3 = f2bf(o3);
        ushort4 hvv = make_ushort4(h0, h1, h2, h3);
        ushort4 lvv = make_ushort4(f2bf(o0 - bf2f(h0)), f2bf(o1 - bf2f(h1)),
                                   f2bf(o2 - bf2f(h2)), f2bf(o3 - bf2f(h3)));
        *(ushort4*)&outH[(size_t)wid * 128 + 4 * l32] = hvv;
        *(ushort4*)&outL[(size_t)wid * 128 + 4 * l32] = lvv;
    }
}

extern "C" void kernel_launch(void* const* d_in, const int* in_sizes, int n_in,
                              void* d_out, int out_size, void* d_ws, size_t ws_size,
                              hipStream_t stream) {
    (void)in_sizes; (void)n_in; (void)out_size; (void)ws_size;

    const float* x       = (const float*)d_in[0];
    const int*   ei      = (const int*)d_in[1];
    const float* sat_W   = (const float*)d_in[2];
    const float* sat_b   = (const float*)d_in[3];
    const float* neigh_W = (const float*)d_in[4];
    const float* neigh_b = (const float*)d_in[5];
    const float* c1_W    = (const float*)d_in[6];
    const float* c1_as   = (const float*)d_in[7];
    const float* c1_ad   = (const float*)d_in[8];
    const float* c1_b    = (const float*)d_in[9];
    const float* c2_W    = (const float*)d_in[10];
    const float* c2_as   = (const float*)d_in[11];
    const float* c2_ad   = (const float*)d_in[12];
    const float* c2_b    = (const float*)d_in[13];
    const float* fc1_W   = (const float*)d_in[14];
    const float* fc1_b   = (const float*)d_in[15];
    const float* fc2_W   = (const float*)d_in[16];
    const float* fc2_b   = (const float*)d_in[17];

    const int* e_src = ei;
    const int* e_dst = ei + N_EDGES;

    char* w = (char*)d_ws;
    u16*   hG     = (u16*)  (w);                  // [N,128] bf16 (gather)
    u16*   hH     = (u16*)  (w + 10240000);       // [N,128] bf16 hi
    u16*   hL     = (u16*)  (w + 20480000);       // [N,128] bf16 lo
    float* as_    = (float*)(w + 30720000);
    float* ad_    = (float*)(w + 30880000);
    int*   deg    = (int*)  (w + 31040000);
    int*   start  = (int*)  (w + 31200000);
    int*   cursor = (int*)  (w + 31360000);
    int*   counter= (int*)  (w + 31520000);
    int*   csr    = (int*)  (w + 31520256);       // [680000]
    u16*   wa     = (u16*)  (w + 34240256);       // weights hi/lo

    u16 *satH = wa,          *satL = wa + 8192;
    u16 *neiH = wa + 16384,  *neiL = wa + 24576;
    u16 *c1H  = wa + 32768,  *c1L  = wa + 49152;
    u16 *c2H  = wa + 65536,  *c2L  = wa + 81920;
    u16 *f1H  = wa + 98304,  *f1L  = wa + 114688;
    u16 *f2H  = wa + 131072, *f2L  = wa + 139264;

    dim3 b(256);
    k_wcvt<<<dim3(64, 6), b, 0, stream>>>(sat_W, neigh_W, c1_W, c2_W, fc1_W, fc2_W,
                                          wa, deg, counter);
    k_deg_count <<<2500, b, 0, stream>>>(e_dst, deg);
    k_assign    <<<157,  b, 0, stream>>>(deg, counter, start, cursor, csr);
    k_fill_edges<<<2500, b, 0, stream>>>(e_src, e_dst, cursor, csr);

    k_enc_conv1<<<625, b, 0, stream>>>(x, satH, satL, neiH, neiL, sat_b, neigh_b,
                                       c1H, c1L, c1_as, c1_ad, hG, as_, ad_);
    k_aggregate<<<10000, b, 0, stream>>>(hG, as_, ad_, start, deg, csr, c1_b, hH, hL);

    k_conv_gemm<<<625, b, 0, stream>>>(hH, hL, c2H, c2L, c2_as, c2_ad, hG, as_, ad_);
    k_aggregate<<<10000, b, 0, stream>>>(hG, as_, ad_, start, deg, csr, c2_b, hH, hL);

    k_fc12<<<625, b, 0, stream>>>(hH, hL, f1H, f1L, fc1_b, f2H, f2L, fc2_b,
                                  (float*)d_out);
}

// Round 8
// 202.358 us; speedup vs baseline: 1.3173x; 1.0541x over previous
//
#include <hip/hip_runtime.h>

// Stage2GNN v8: v7 + LDS overlay. In k_enc_conv1 and k_fc12, the W-staging
// buffer and the f32 h staging tile are NEVER live at the same time
// (barrier-separated phases), so they alias in ONE 32KB buffer:
// LDS 64KB->32KB, occupancy 2->5 blocks/CU on the fused kernels.
// Arithmetic identical to v7 -> absmax 0.00390625.

#define N_NODES 40000
#define N_EDGES 640000
#define DIM     128

typedef unsigned short u16;
typedef __attribute__((ext_vector_type(8))) short bf16x8;
typedef __attribute__((ext_vector_type(4))) float f32x4;

__device__ __forceinline__ u16 f2bf(float v) {
    unsigned u = __float_as_uint(v);
    u += 0x7FFFu + ((u >> 16) & 1u);
    return (u16)(u >> 16);
}
__device__ __forceinline__ float bf2f(u16 h) { return __uint_as_float(((unsigned)h) << 16); }
__device__ __forceinline__ float rdlane_f(float v, int l) {
    return __uint_as_float(__builtin_amdgcn_readlane(__float_as_uint(v), l));
}

// swizzled f32 LDS tile [64][128]: 4-f32 block b of row r stored at b^(r&7)
__device__ __forceinline__ int hswz(int row, int col) {
    return row * 128 + ((((col >> 2) ^ (row & 7))) << 2) + (col & 3);
}
__device__ __forceinline__ float4 hread4(const float* hbuf, int row, int k) {  // k mult of 4
    int b = (k >> 2) ^ (row & 7);
    return *(const float4*)&hbuf[row * 128 + (b << 2)];
}
__device__ __forceinline__ void split8(const float* vv, bf16x8& hi, bf16x8& lo) {
#pragma unroll
    for (int i = 0; i < 8; ++i) {
        u16 h = f2bf(vv[i]);
        hi[i] = (short)h;
        lo[i] = (short)f2bf(vv[i] - bf2f(h));
    }
}

// ---------------- weight conversion + deg/counter init ----------------
__global__ __launch_bounds__(256) void k_wcvt(
    const float* __restrict__ satW, const float* __restrict__ neiW,
    const float* __restrict__ c1W, const float* __restrict__ c2W,
    const float* __restrict__ f1W, const float* __restrict__ f2W,
    u16* __restrict__ wa, int* __restrict__ deg, int* __restrict__ counter) {
    int gid = (blockIdx.y * gridDim.x + blockIdx.x) * 256 + threadIdx.x;
    if (gid < N_NODES) deg[gid] = 1;   // self loop
    if (gid == 0) *counter = 0;

    int m = blockIdx.y;
    const float* src; int C, K, Cp; int offH, offL;
    switch (m) {
        case 0: src = satW; C = 128; K = 64;  Cp = 128; offH = 0;      offL = 8192;   break;
        case 1: src = neiW; C = 128; K = 64;  Cp = 128; offH = 16384;  offL = 24576;  break;
        case 2: src = c1W;  C = 128; K = 128; Cp = 128; offH = 32768;  offL = 49152;  break;
        case 3: src = c2W;  C = 128; K = 128; Cp = 128; offH = 65536;  offL = 81920;  break;
        case 4: src = f1W;  C = 128; K = 128; Cp = 128; offH = 98304;  offL = 114688; break;
        default:src = f2W;  C = 54;  K = 128; Cp = 64;  offH = 131072; offL = 139264; break;
    }
    int e = blockIdx.x * 256 + threadIdx.x;
    if (e >= Cp * K) return;
    int c = e / K, k = e - c * K;
    float v = (c < C) ? src[c * K + k] : 0.f;
    u16 h = f2bf(v);
    wa[offH + e] = h;
    wa[offL + e] = f2bf(v - bf2f(h));
}

// ---------------- CSR build ----------------
__global__ void k_deg_count(const int* __restrict__ dst, int* __restrict__ deg) {
    int t = blockIdx.x * 256 + threadIdx.x;
    if (t < N_EDGES) atomicAdd(&deg[dst[t]], 1);
}
__global__ void k_assign(const int* __restrict__ deg, int* __restrict__ counter,
                         int* __restrict__ start, int* __restrict__ cursor,
                         int* __restrict__ csr_src) {
    int i = blockIdx.x * 256 + threadIdx.x;
    if (i >= N_NODES) return;
    int d = deg[i];
    int s = atomicAdd(counter, d);
    start[i] = s;
    csr_src[s] = i;
    cursor[i] = s + 1;
}
__global__ void k_fill_edges(const int* __restrict__ src, const int* __restrict__ dst,
                             int* __restrict__ cursor, int* __restrict__ csr_src) {
    int t = blockIdx.x * 256 + threadIdx.x;
    if (t < N_EDGES) {
        int p = atomicAdd(&cursor[dst[t]], 1);
        csr_src[p] = src[t];
    }
}

// ---------------- shared GEMM pieces ----------------
// W staging into LDS fragment order: idx = [ct][ks2][hilo2][lane64]
template<int CT>
__device__ __forceinline__ void stage_W(u16* Ws, const u16* __restrict__ Wh,
                                        const u16* __restrict__ Wl, int kc, int tid) {
    for (int idx = tid; idx < CT * 2 * 2 * 64; idx += 256) {
        int l = idx & 63;
        int q = idx >> 6;
        int hilo = q & 1;
        int ks = (q >> 1) & 1;
        int ct = q >> 2;
        int c = ct * 16 + (l & 15);
        int k = kc * 64 + ks * 32 + (l >> 4) * 8;
        const u16* Wp = hilo ? Wl : Wh;
        *reinterpret_cast<bf16x8*>(&Ws[idx * 8]) =
            *reinterpret_cast<const bf16x8*>(Wp + (size_t)c * 128 + k);
    }
}

#define MFMA3(ACC, AH, AL, BH, BL)                                             \
    ACC = __builtin_amdgcn_mfma_f32_16x16x32_bf16(AH, BH, ACC, 0, 0, 0);       \
    ACC = __builtin_amdgcn_mfma_f32_16x16x32_bf16(AH, BL, ACC, 0, 0, 0);       \
    ACC = __builtin_amdgcn_mfma_f32_16x16x32_bf16(AL, BH, ACC, 0, 0, 0);

// alpha epilogue: as_/ad_ from f32 accumulators
__device__ __forceinline__ void alpha_epi(const f32x4* acc, int lane, int r0,
                                          const float* __restrict__ a_src,
                                          const float* __restrict__ a_dst,
                                          float* __restrict__ as_, float* __restrict__ ad_) {
    float ps[4] = {0, 0, 0, 0}, pd[4] = {0, 0, 0, 0};
#pragma unroll
    for (int ct = 0; ct < 8; ++ct) {
        float asv = a_src[ct * 16 + (lane & 15)];
        float adv = a_dst[ct * 16 + (lane & 15)];
#pragma unroll
        for (int r = 0; r < 4; ++r) {
            ps[r] = fmaf(acc[ct][r], asv, ps[r]);
            pd[r] = fmaf(acc[ct][r], adv, pd[r]);
        }
    }
#pragma unroll
    for (int off = 1; off < 16; off <<= 1) {
#pragma unroll
        for (int r = 0; r < 4; ++r) {
            ps[r] += __shfl_xor(ps[r], off);
            pd[r] += __shfl_xor(pd[r], off);
        }
    }
    if ((lane & 15) == 0) {
#pragma unroll
        for (int r = 0; r < 4; ++r) {
            int row = r0 + (lane >> 4) * 4 + r;
            as_[row] = ps[r];
            ad_[row] = pd[r];
        }
    }
}

// ---------------- fused encoder + conv1 GEMM (single 32KB LDS buffer) ----------------
__global__ __launch_bounds__(256) void k_enc_conv1(
    const float* __restrict__ x,
    const u16* __restrict__ sH, const u16* __restrict__ sL,
    const u16* __restrict__ nH, const u16* __restrict__ nL,
    const float* __restrict__ satb, const float* __restrict__ neib,
    const u16* __restrict__ Wh, const u16* __restrict__ Wl,   // conv1
    const float* __restrict__ a_src, const float* __restrict__ a_dst,
    u16* __restrict__ outG, float* __restrict__ as_, float* __restrict__ ad_)
{
    __shared__ u16 Wbuf[16384];          // 32KB total; phases: encW -> h(f32) -> conv1W
    float* hbuf = (float*)Wbuf;          // overlay (barrier-separated liveness)
    const int tid = threadIdx.x, lane = tid & 63, wv = tid >> 6;
    const int r0 = blockIdx.x * 64 + wv * 16;
    const int arow = r0 + (lane & 15);
    const int kb = (lane >> 4) * 8;

    // x fragments: f32 -> split bf16 in registers
    bf16x8 axh[4], axl[4];
#pragma unroll
    for (int s = 0; s < 4; ++s) {
        const float* p = x + (size_t)arow * 128 + s * 32 + kb;
        float4 a = *(const float4*)p;
        float4 b = *(const float4*)(p + 4);
        float vv[8] = {a.x, a.y, a.z, a.w, b.x, b.y, b.z, b.w};
        split8(vv, axh[s], axl[s]);
    }

    f32x4 accS[8], accN[8];
#pragma unroll
    for (int ct = 0; ct < 8; ++ct) { accS[ct] = (f32x4){0,0,0,0}; accN[ct] = (f32x4){0,0,0,0}; }

    // encoder: sat (x cols 0-63), nei (x cols 64-127); K=64 each
#pragma unroll
    for (int mat = 0; mat < 2; ++mat) {
        if (mat) __syncthreads();
        const u16* WH = mat ? nH : sH;
        const u16* WL = mat ? nL : sL;
        for (int idx = tid; idx < 2048; idx += 256) {
            int l = idx & 63;
            int q = idx >> 6;
            int hilo = q & 1;
            int ks = (q >> 1) & 1;
            int ct = q >> 2;
            int c = ct * 16 + (l & 15);
            int k = ks * 32 + (l >> 4) * 8;
            const u16* Wp = hilo ? WL : WH;
            *reinterpret_cast<bf16x8*>(&Wbuf[idx * 8]) =
                *reinterpret_cast<const bf16x8*>(Wp + (size_t)c * 64 + k);
        }
        __syncthreads();
#pragma unroll
        for (int ct = 0; ct < 8; ++ct) {
#pragma unroll
            for (int ks = 0; ks < 2; ++ks) {
                int s = mat * 2 + ks;
                int base = (ct * 2 + ks) * 1024;
                bf16x8 bh = *reinterpret_cast<const bf16x8*>(&Wbuf[base + lane * 8]);
                bf16x8 bl = *reinterpret_cast<const bf16x8*>(&Wbuf[base + 512 + lane * 8]);
                f32x4* ac = mat ? &accN[ct] : &accS[ct];
                MFMA3((*ac), axh[s], axl[s], bh, bl);
            }
        }
    }
    __syncthreads();   // encoder done reading Wbuf -> safe to overlay h

    // h -> LDS (f32, swizzled), overlaying the W buffer
#pragma unroll
    for (int ct = 0; ct < 8; ++ct) {
        int c = ct * 16 + (lane & 15);
        float bs = satb[c], bn = neib[c];
#pragma unroll
        for (int r = 0; r < 4; ++r) {
            int rl = wv * 16 + (lane >> 4) * 4 + r;
            float v = fmaxf(accS[ct][r] + bs, 0.f) + 0.5f * fmaxf(accN[ct][r] + bn, 0.f);
            hbuf[hswz(rl, c)] = v;
        }
    }
    __syncthreads();

    // conv1 A fragments from LDS
    bf16x8 ah[4], al[4];
    const int ar = wv * 16 + (lane & 15);
#pragma unroll
    for (int s = 0; s < 4; ++s) {
        int k0 = s * 32 + kb;
        float4 a = hread4(hbuf, ar, k0);
        float4 b = hread4(hbuf, ar, k0 + 4);
        float vv[8] = {a.x, a.y, a.z, a.w, b.x, b.y, b.z, b.w};
        split8(vv, ah[s], al[s]);
    }
    __syncthreads();   // h reads done -> safe to overlay conv1 W

    f32x4 acc[8];
#pragma unroll
    for (int ct = 0; ct < 8; ++ct) acc[ct] = (f32x4){0, 0, 0, 0};
#pragma unroll
    for (int kc = 0; kc < 2; ++kc) {
        if (kc) __syncthreads();
        stage_W<8>(Wbuf, Wh, Wl, kc, tid);
        __syncthreads();
#pragma unroll
        for (int ct = 0; ct < 8; ++ct) {
#pragma unroll
            for (int ks = 0; ks < 2; ++ks) {
                int s = kc * 2 + ks;
                int base = (ct * 2 + ks) * 1024;
                bf16x8 bh = *reinterpret_cast<const bf16x8*>(&Wbuf[base + lane * 8]);
                bf16x8 bl = *reinterpret_cast<const bf16x8*>(&Wbuf[base + 512 + lane * 8]);
                MFMA3(acc[ct], ah[s], al[s], bh, bl);
            }
        }
    }

    alpha_epi(acc, lane, r0, a_src, a_dst, as_, ad_);

#pragma unroll
    for (int ct = 0; ct < 8; ++ct) {
        int c = ct * 16 + (lane & 15);
#pragma unroll
        for (int r = 0; r < 4; ++r) {
            int row = r0 + (lane >> 4) * 4 + r;
            outG[(size_t)row * 128 + c] = f2bf(acc[ct][r]);
        }
    }
}

// ---------------- conv2 GEMM (+alpha), A from global hi/lo ----------------
__global__ __launch_bounds__(256) void k_conv_gemm(
    const u16* __restrict__ Ah, const u16* __restrict__ Al,
    const u16* __restrict__ Wh, const u16* __restrict__ Wl,
    const float* __restrict__ a_src, const float* __restrict__ a_dst,
    u16* __restrict__ outG, float* __restrict__ as_, float* __restrict__ ad_)
{
    __shared__ u16 Wbuf[16384];
    const int tid = threadIdx.x, lane = tid & 63, wv = tid >> 6;
    const int r0 = blockIdx.x * 64 + wv * 16;
    const int arow = r0 + (lane & 15);
    const int kb = (lane >> 4) * 8;

    bf16x8 ah[4], al[4];
#pragma unroll
    for (int s = 0; s < 4; ++s) {
        ah[s] = *reinterpret_cast<const bf16x8*>(Ah + (size_t)arow * 128 + s * 32 + kb);
        al[s] = *reinterpret_cast<const bf16x8*>(Al + (size_t)arow * 128 + s * 32 + kb);
    }

    f32x4 acc[8];
#pragma unroll
    for (int ct = 0; ct < 8; ++ct) acc[ct] = (f32x4){0, 0, 0, 0};
#pragma unroll
    for (int kc = 0; kc < 2; ++kc) {
        if (kc) __syncthreads();
        stage_W<8>(Wbuf, Wh, Wl, kc, tid);
        __syncthreads();
#pragma unroll
        for (int ct = 0; ct < 8; ++ct) {
#pragma unroll
            for (int ks = 0; ks < 2; ++ks) {
                int s = kc * 2 + ks;
                int base = (ct * 2 + ks) * 1024;
                bf16x8 bh = *reinterpret_cast<const bf16x8*>(&Wbuf[base + lane * 8]);
                bf16x8 bl = *reinterpret_cast<const bf16x8*>(&Wbuf[base + 512 + lane * 8]);
                MFMA3(acc[ct], ah[s], al[s], bh, bl);
            }
        }
    }

    alpha_epi(acc, lane, r0, a_src, a_dst, as_, ad_);

#pragma unroll
    for (int ct = 0; ct < 8; ++ct) {
        int c = ct * 16 + (lane & 15);
#pragma unroll
        for (int r = 0; r < 4; ++r) {
            int row = r0 + (lane >> 4) * 4 + r;
            outG[(size_t)row * 128 + c] = f2bf(acc[ct][r]);
        }
    }
}

// ---------------- fused fc1 + fc2 (single 32KB LDS buffer) ----------------
__global__ __launch_bounds__(256) void k_fc12(
    const u16* __restrict__ Ah, const u16* __restrict__ Al,
    const u16* __restrict__ W1h, const u16* __restrict__ W1l, const float* __restrict__ b1,
    const u16* __restrict__ W2h, const u16* __restrict__ W2l, const float* __restrict__ b2,
    float* __restrict__ out)
{
    __shared__ u16 Wbuf[16384];    // 32KB; phases: fc1 W -> f32 h' -> fc2 W
    float* hbuf = (float*)Wbuf;
    const int tid = threadIdx.x, lane = tid & 63, wv = tid >> 6;
    const int r0 = blockIdx.x * 64 + wv * 16;
    const int arow = r0 + (lane & 15);
    const int kb = (lane >> 4) * 8;

    bf16x8 ah[4], al[4];
#pragma unroll
    for (int s = 0; s < 4; ++s) {
        ah[s] = *reinterpret_cast<const bf16x8*>(Ah + (size_t)arow * 128 + s * 32 + kb);
        al[s] = *reinterpret_cast<const bf16x8*>(Al + (size_t)arow * 128 + s * 32 + kb);
    }

    f32x4 acc[8];
#pragma unroll
    for (int ct = 0; ct < 8; ++ct) acc[ct] = (f32x4){0, 0, 0, 0};
#pragma unroll
    for (int kc = 0; kc < 2; ++kc) {
        if (kc) __syncthreads();
        stage_W<8>(Wbuf, W1h, W1l, kc, tid);
        __syncthreads();
#pragma unroll
        for (int ct = 0; ct < 8; ++ct) {
#pragma unroll
            for (int ks = 0; ks < 2; ++ks) {
                int s = kc * 2 + ks;
                int base = (ct * 2 + ks) * 1024;
                bf16x8 bh = *reinterpret_cast<const bf16x8*>(&Wbuf[base + lane * 8]);
                bf16x8 bl = *reinterpret_cast<const bf16x8*>(&Wbuf[base + 512 + lane * 8]);
                MFMA3(acc[ct], ah[s], al[s], bh, bl);
            }
        }
    }
    __syncthreads();   // all waves done reading fc1 W

    // h' = relu(fc1 + b1) -> LDS f32 (overlay)
#pragma unroll
    for (int ct = 0; ct < 8; ++ct) {
        int c = ct * 16 + (lane & 15);
        float bv = b1[c];
#pragma unroll
        for (int r = 0; r < 4; ++r) {
            int rl = wv * 16 + (lane >> 4) * 4 + r;
            hbuf[hswz(rl, c)] = fmaxf(acc[ct][r] + bv, 0.f);
        }
    }
    __syncthreads();

    // fc2 A fragments from LDS
    bf16x8 a2h[4], a2l[4];
    const int ar = wv * 16 + (lane & 15);
#pragma unroll
    for (int s = 0; s < 4; ++s) {
        int k0 = s * 32 + kb;
        float4 a = hread4(hbuf, ar, k0);
        float4 b = hread4(hbuf, ar, k0 + 4);
        float vv[8] = {a.x, a.y, a.z, a.w, b.x, b.y, b.z, b.w};
        split8(vv, a2h[s], a2l[s]);
    }
    __syncthreads();   // h' reads done -> safe to overlay fc2 W

    f32x4 acc2[4];
#pragma unroll
    for (int ct = 0; ct < 4; ++ct) acc2[ct] = (f32x4){0, 0, 0, 0};
#pragma unroll
    for (int kc = 0; kc < 2; ++kc) {
        if (kc) __syncthreads();
        stage_W<4>(Wbuf, W2h, W2l, kc, tid);
        __syncthreads();
#pragma unroll
        for (int ct = 0; ct < 4; ++ct) {
#pragma unroll
            for (int ks = 0; ks < 2; ++ks) {
                int s = kc * 2 + ks;
                int base = (ct * 2 + ks) * 1024;
                bf16x8 bh = *reinterpret_cast<const bf16x8*>(&Wbuf[base + lane * 8]);
                bf16x8 bl = *reinterpret_cast<const bf16x8*>(&Wbuf[base + 512 + lane * 8]);
                MFMA3(acc2[ct], a2h[s], a2l[s], bh, bl);
            }
        }
    }

#pragma unroll
    for (int ct = 0; ct < 4; ++ct) {
        int c = ct * 16 + (lane & 15);
#pragma unroll
        for (int r = 0; r < 4; ++r) {
            int row = r0 + (lane >> 4) * 4 + r;
            if (c < 54) out[(size_t)row * 54 + c] = acc2[ct][r] + b2[c];
        }
    }
}

// ---------------- wave-per-node softmax + aggregation (bf16 gather) ----------------
#define DO_PAIRS(NP, TB)                                                      \
    {                                                                         \
        float pw[NP]; const ushort4* hp[NP];                                  \
        _Pragma("unroll")                                                     \
        for (int q = 0; q < NP; ++q) {                                        \
            int e0 = (TB) + 2 * q;                                            \
            float plo = rdlane_f(p, e0), phi = rdlane_f(p, e0 + 1);           \
            int jlo = __builtin_amdgcn_readlane(jj, e0);                      \
            int jhi = __builtin_amdgcn_readlane(jj, e0 + 1);                  \
            pw[q] = hodd ? phi : plo;                                         \
            int j = hodd ? jhi : jlo;                                         \
            hp[q] = (const ushort4*)&hg[(size_t)j * 128 + 4 * l32];           \
        }                                                                     \
        ushort4 hv[NP];                                                       \
        _Pragma("unroll") for (int q = 0; q < NP; ++q) hv[q] = *hp[q];        \
        _Pragma("unroll") for (int q = 0; q < NP; ++q) {                      \
            acc.x = fmaf(pw[q], bf2f(hv[q].x), acc.x);                        \
            acc.y = fmaf(pw[q], bf2f(hv[q].y), acc.y);                        \
            acc.z = fmaf(pw[q], bf2f(hv[q].z), acc.z);                        \
            acc.w = fmaf(pw[q], bf2f(hv[q].w), acc.w);                        \
        }                                                                     \
    }

__global__ __launch_bounds__(256) void k_aggregate(
    const u16* __restrict__ hg, const float* __restrict__ as_,
    const float* __restrict__ ad_, const int* __restrict__ start,
    const int* __restrict__ deg, const int* __restrict__ csr_src,
    const float* __restrict__ bias, u16* __restrict__ outH, u16* __restrict__ outL)
{
    int wid = (blockIdx.x * 256 + threadIdx.x) >> 6;
    int lane = threadIdx.x & 63;
    if (wid >= N_NODES) return;

    const int s0 = start[wid];
    const int s1 = s0 + deg[wid];
    const float adi = ad_[wid];
    const int l32 = lane & 31;
    const bool hodd = lane >= 32;

    float4 acc = make_float4(0.f, 0.f, 0.f, 0.f);
    float ssum = 0.f;
    for (int base = s0; base < s1; base += 64) {
        int k = base + lane;
        int cnt = min(64, s1 - base);   // wave-uniform
        int jj = 0;
        float p = 0.f;
        if (k < s1) {
            jj = csr_src[k];
            float e = as_[jj] + adi;
            e = (e > 0.f) ? e : 0.2f * e;
            p = __expf(e);              // |e| << 88: no max-shift needed
            ssum += p;
        }
        int t = 0;
        for (; t + 16 <= cnt; t += 16) DO_PAIRS(8, t)
        if (t + 8 <= cnt) { DO_PAIRS(4, t) t += 8; }
        if (t + 4 <= cnt) { DO_PAIRS(2, t) t += 4; }
        for (; t < cnt; t += 2) DO_PAIRS(1, t)
    }
#pragma unroll
    for (int off = 32; off; off >>= 1) ssum += __shfl_xor(ssum, off);
    acc.x += __shfl_xor(acc.x, 32);
    acc.y += __shfl_xor(acc.y, 32);
    acc.z += __shfl_xor(acc.z, 32);
    acc.w += __shfl_xor(acc.w, 32);
    float inv = 1.f / (ssum + 1e-16f);

    if (!hodd) {
        float4 bv = *(const float4*)&bias[4 * l32];
        float o0 = fmaxf(fmaf(acc.x, inv, bv.x), 0.f);
        float o1 = fmaxf(fmaf(acc.y, inv, bv.y), 0.f);
        float o2 = fmaxf(fmaf(acc.z, inv, bv.z), 0.f);
        float o3 = fmaxf(fmaf(acc.w, inv, bv.w), 0.f);
        u16 h0 = f2bf(o0), h1 = f2bf(o1), h2 = f2bf(o2), h3 = f2bf(o3);
        ushort4 hvv = make_ushort4(h0, h1, h2, h3);
        ushort4 lvv = make_ushort4(f2bf(o0 - bf2f(h0)), f2bf(o1 - bf2f(h1)),
                                   f2bf(o2 - bf2f(h2)), f2bf(o3 - bf2f(h3)));
        *(ushort4*)&outH[(size_t)wid * 128 + 4 * l32] = hvv;
        *(ushort4*)&outL[(size_t)wid * 128 + 4 * l32] = lvv;
    }
}

extern "C" void kernel_launch(void* const* d_in, const int* in_sizes, int n_in,
                              void* d_out, int out_size, void* d_ws, size_t ws_size,
                              hipStream_t stream) {
    (void)in_sizes; (void)n_in; (void)out_size; (void)ws_size;

    const float* x       = (const float*)d_in[0];
    const int*   ei      = (const int*)d_in[1];
    const float* sat_W   = (const float*)d_in[2];
    const float* sat_b   = (const float*)d_in[3];
    const float* neigh_W = (const float*)d_in[4];
    const float* neigh_b = (const float*)d_in[5];
    const float* c1_W    = (const float*)d_in[6];
    const float* c1_as   = (const float*)d_in[7];
    const float* c1_ad   = (const float*)d_in[8];
    const float* c1_b    = (const float*)d_in[9];
    const float* c2_W    = (const float*)d_in[10];
    const float* c2_as   = (const float*)d_in[11];
    const float* c2_ad   = (const float*)d_in[12];
    const float* c2_b    = (const float*)d_in[13];
    const float* fc1_W   = (const float*)d_in[14];
    const float* fc1_b   = (const float*)d_in[15];
    const float* fc2_W   = (const float*)d_in[16];
    const float* fc2_b   = (const float*)d_in[17];

    const int* e_src = ei;
    const int* e_dst = ei + N_EDGES;

    char* w = (char*)d_ws;
    u16*   hG     = (u16*)  (w);                  // [N,128] bf16 (gather)
    u16*   hH     = (u16*)  (w + 10240000);       // [N,128] bf16 hi
    u16*   hL     = (u16*)  (w + 20480000);       // [N,128] bf16 lo
    float* as_    = (float*)(w + 30720000);
    float* ad_    = (float*)(w + 30880000);
    int*   deg    = (int*)  (w + 31040000);
    int*   start  = (int*)  (w + 31200000);
    int*   cursor = (int*)  (w + 31360000);
    int*   counter= (int*)  (w + 31520000);
    int*   csr    = (int*)  (w + 31520256);       // [680000]
    u16*   wa     = (u16*)  (w + 34240256);       // weights hi/lo

    u16 *satH = wa,          *satL = wa + 8192;
    u16 *neiH = wa + 16384,  *neiL = wa + 24576;
    u16 *c1H  = wa + 32768,  *c1L  = wa + 49152;
    u16 *c2H  = wa + 65536,  *c2L  = wa + 81920;
    u16 *f1H  = wa + 98304,  *f1L  = wa + 114688;
    u16 *f2H  = wa + 131072, *f2L  = wa + 139264;

    dim3 b(256);
    k_wcvt<<<dim3(64, 6), b, 0, stream>>>(sat_W, neigh_W, c1_W, c2_W, fc1_W, fc2_W,
                                          wa, deg, counter);
    k_deg_count <<<2500, b, 0, stream>>>(e_dst, deg);
    k_assign    <<<157,  b, 0, stream>>>(deg, counter, start, cursor, csr);
    k_fill_edges<<<2500, b, 0, stream>>>(e_src, e_dst, cursor, csr);

    k_enc_conv1<<<625, b, 0, stream>>>(x, satH, satL, neiH, neiL, sat_b, neigh_b,
                                       c1H, c1L, c1_as, c1_ad, hG, as_, ad_);
    k_aggregate<<<10000, b, 0, stream>>>(hG, as_, ad_, start, deg, csr, c1_b, hH, hL);

    k_conv_gemm<<<625, b, 0, stream>>>(hH, hL, c2H, c2L, c2_as, c2_ad, hG, as_, ad_);
    k_aggregate<<<10000, b, 0, stream>>>(hG, as_, ad_, start, deg, csr, c2_b, hH, hL);

    k_fc12<<<625, b, 0, stream>>>(hH, hL, f1H, f1L, fc1_b, f2H, f2L, fc2_b,
                                  (float*)d_out);
}